// Round 1
// baseline (2457.487 us; speedup 1.0000x reference)
//
#include <hip/hip_runtime.h>

#define D_ 1536
#define H_ 8

// ---------------- V_src / V_dst: V[d,h] = sum_d2 W[d, h*D+d2] * att[h,d2] ----------------
__global__ __launch_bounds__(256) void k_vmat(const float* __restrict__ Wsrc,
                                              const float* __restrict__ Wdst,
                                              const float* __restrict__ att_s,
                                              const float* __restrict__ att_d,
                                              float* __restrict__ Vsrc,
                                              float* __restrict__ Vdst) {
    int id = blockIdx.x;
    int sel = id >= (D_ * H_);
    int idx = sel ? id - D_ * H_ : id;
    int d = idx >> 3, h = idx & 7;
    const float* W = (sel ? Wdst : Wsrc) + (size_t)d * (H_ * D_) + (size_t)h * D_;
    const float* at = (sel ? att_d : att_s) + (size_t)h * D_;
    float s = 0.f;
    for (int i = threadIdx.x; i < D_; i += 256) s += W[i] * at[i];
    for (int o = 32; o; o >>= 1) s += __shfl_down(s, o);
    __shared__ float red[4];
    if ((threadIdx.x & 63) == 0) red[threadIdx.x >> 6] = s;
    __syncthreads();
    if (threadIdx.x == 0) (sel ? Vdst : Vsrc)[d * H_ + h] = red[0] + red[1] + red[2] + red[3];
}

// ---------------- a = x @ V  ([N,D] x [D,H] -> [N,H]) ----------------
__global__ __launch_bounds__(256) void k_a(const float* __restrict__ x,
                                           const float* __restrict__ V,
                                           float* __restrict__ out, int N) {
    int n = blockIdx.x;
    if (n >= N) return;
    float part[H_] = {};
    const float* xr = x + (size_t)n * D_;
    #pragma unroll
    for (int j = 0; j < 6; j++) {
        int d = threadIdx.x + j * 256;
        float xv = xr[d];
        const float* vp = V + d * H_;
        #pragma unroll
        for (int h = 0; h < H_; h++) part[h] += xv * vp[h];
    }
    __shared__ float red[4][H_];
    int lane = threadIdx.x & 63, w = threadIdx.x >> 6;
    #pragma unroll
    for (int h = 0; h < H_; h++) {
        float v = part[h];
        for (int o = 32; o; o >>= 1) v += __shfl_down(v, o);
        if (lane == 0) red[w][h] = v;
    }
    __syncthreads();
    if (threadIdx.x < H_)
        out[(size_t)n * H_ + threadIdx.x] =
            red[0][threadIdx.x] + red[1][threadIdx.x] + red[2][threadIdx.x] + red[3][threadIdx.x];
}

// ---------------- edge counting sort ----------------
__global__ void k_count(const int* __restrict__ dj, int ej, const int* __restrict__ dr, int er,
                        int* cnt_j, int* cnt_r) {
    int i = blockIdx.x * blockDim.x + threadIdx.x;
    if (i < ej) atomicAdd(&cnt_j[dj[i]], 1);
    else if (i < ej + er) atomicAdd(&cnt_r[dr[i - ej]], 1);
}

__global__ void k_scan(const int* __restrict__ cnt_j, int* off_j,
                       const int* __restrict__ cnt_r, int* off_r, int NP) {
    const int* cnt = blockIdx.x ? cnt_r : cnt_j;
    int* off = blockIdx.x ? off_r : off_j;
    int lane = threadIdx.x;
    int chunk = (NP + 63) / 64;
    int base = lane * chunk;
    int sum = 0;
    for (int i = 0; i < chunk; i++) { int idx = base + i; if (idx < NP) sum += cnt[idx]; }
    int incl = sum;
    for (int o = 1; o < 64; o <<= 1) { int t = __shfl_up(incl, o); if (lane >= o) incl += t; }
    int run = incl - sum;
    for (int i = 0; i < chunk; i++) { int idx = base + i; if (idx < NP) { off[idx] = run; run += cnt[idx]; } }
    if (lane == 63) off[NP] = run;
}

__global__ void k_scatter(const int* __restrict__ dj, int ej, const int* __restrict__ dr, int er,
                          const int* __restrict__ off_j, int* fill_j, int* sid_j,
                          const int* __restrict__ off_r, int* fill_r, int* sid_r) {
    int i = blockIdx.x * blockDim.x + threadIdx.x;
    if (i < ej) {
        int p = dj[i];
        int slot = atomicAdd(&fill_j[p], 1);
        sid_j[off_j[p] + slot] = i;
    } else if (i < ej + er) {
        int e = i - ej;
        int p = dr[e];
        int slot = atomicAdd(&fill_r[p], 1);
        sid_r[off_r[p] + slot] = e;
    }
}

// ---------------- GraphConv aggregate: agg[p] = sum x_skill[src_e] ----------------
__global__ __launch_bounds__(256) void k_agg(const float* __restrict__ x, const int* __restrict__ src,
                                             const int* __restrict__ sid, const int* __restrict__ cnt,
                                             const int* __restrict__ off, float* __restrict__ agg) {
    int p = blockIdx.x;
    int n = cnt[p], o = off[p];
    float acc[6] = {};
    for (int i = 0; i < n; i++) {
        int e = sid[o + i];
        const float* xr = x + (size_t)src[e] * D_ + threadIdx.x;
        #pragma unroll
        for (int j = 0; j < 6; j++) acc[j] += xr[j * 256];
    }
    float* orow = agg + (size_t)p * D_ + threadIdx.x;
    #pragma unroll
    for (int j = 0; j < 6; j++) orow[j * 256] = acc[j];
}

// ---------------- GAT segment softmax -> alpha (original edge order) ----------------
__global__ void k_softmax(const float* __restrict__ a_src, const float* __restrict__ a_dst,
                          const int* __restrict__ src, const int* __restrict__ sid,
                          const int* __restrict__ cnt, const int* __restrict__ off,
                          float* __restrict__ alpha_out) {
    int p = blockIdx.x;
    int n = cnt[p], o = off[p];
    if (n == 0) return;
    int lane = threadIdx.x;
    #pragma unroll 1
    for (int h = 0; h < H_; h++) {
        float ad = a_dst[(size_t)p * H_ + h];
        float m = -3.4e38f;
        for (int i = lane; i < n; i += 64) {
            int e = sid[o + i];
            float v = a_src[(size_t)src[e] * H_ + h] + ad;
            v = v >= 0.f ? v : 0.2f * v;
            m = fmaxf(m, v);
        }
        for (int o2 = 32; o2; o2 >>= 1) m = fmaxf(m, __shfl_xor(m, o2));
        float s = 0.f;
        for (int i = lane; i < n; i += 64) {
            int e = sid[o + i];
            float v = a_src[(size_t)src[e] * H_ + h] + ad;
            v = v >= 0.f ? v : 0.2f * v;
            s += expf(v - m);
        }
        for (int o2 = 32; o2; o2 >>= 1) s += __shfl_xor(s, o2);
        float inv = 1.f / (s + 1e-16f);
        for (int i = lane; i < n; i += 64) {
            int e = sid[o + i];
            float v = a_src[(size_t)src[e] * H_ + h] + ad;
            v = v >= 0.f ? v : 0.2f * v;
            alpha_out[(size_t)e * H_ + h] = expf(v - m) * inv;
        }
    }
}

// ---------------- attention-weighted aggregate in input space ----------------
// agg_att[p, h*D + d] = sum_e alpha[e,h] * x_skill[src_e, d]
__global__ __launch_bounds__(256) void k_aggatt(const float* __restrict__ x,
                                                const float* __restrict__ alpha,
                                                const int* __restrict__ src, const int* __restrict__ sid,
                                                const int* __restrict__ cnt, const int* __restrict__ off,
                                                float* __restrict__ aggatt) {
    int p = blockIdx.x;
    int n = cnt[p], o = off[p];
    float acc[H_][6] = {};
    for (int i = 0; i < n; i++) {
        int e = sid[o + i];
        int s = src[e];
        const float* ap = alpha + (size_t)e * H_;
        float al[H_];
        #pragma unroll
        for (int h = 0; h < H_; h++) al[h] = ap[h];
        const float* xr = x + (size_t)s * D_ + threadIdx.x;
        float xv[6];
        #pragma unroll
        for (int j = 0; j < 6; j++) xv[j] = xr[j * 256];
        #pragma unroll
        for (int h = 0; h < H_; h++)
            #pragma unroll
            for (int j = 0; j < 6; j++) acc[h][j] += al[h] * xv[j];
    }
    float* orow = aggatt + (size_t)p * (H_ * D_) + threadIdx.x;
    #pragma unroll
    for (int h = 0; h < H_; h++)
        #pragma unroll
        for (int j = 0; j < 6; j++) orow[h * D_ + j * 256] = acc[h][j];
}

// ---------------- generic 64x64 fp32 GEMM ----------------
// Cout[m,n] = epilogue( scale * sum_k A[m,k]*B[k,n] )
// GATB=1: B[k,n] = W_gat_src[(k%D)*H*D + (k/D)*D + n]  (stacked per-head weights)
template <int GATB>
__global__ __launch_bounds__(256) void gemm64(const float* __restrict__ A, int lda,
                                              const float* __restrict__ B, int ldb,
                                              const float* __restrict__ Cin, int ldcin,
                                              float* __restrict__ Cout, int ldcout,
                                              const float* __restrict__ bias,
                                              float scale, float slope, int K,
                                              int useCin, int useBias, int useLeaky) {
    __shared__ float As[16][65];
    __shared__ float Bs[16][64];
    int tid = threadIdx.x;
    int bm = blockIdx.y * 64, bn = blockIdx.x * 64;
    int tx = tid & 15, ty = tid >> 4;
    int acol = tid & 15, arow = tid >> 4;
    int bcol = tid & 63, brow = tid >> 6;
    float c[4][4] = {};
    for (int k0 = 0; k0 < K; k0 += 16) {
        #pragma unroll
        for (int i = 0; i < 4; i++) {
            int r = arow + 16 * i;
            As[acol][r] = A[(size_t)(bm + r) * lda + k0 + acol];
        }
        #pragma unroll
        for (int i = 0; i < 4; i++) {
            int r = brow + 4 * i;
            int kk = k0 + r;
            const float* brp;
            if (GATB) {
                int h = kk / D_;
                int d2 = kk - h * D_;
                brp = B + (size_t)d2 * (H_ * D_) + (size_t)h * D_;
            } else {
                brp = B + (size_t)kk * ldb;
            }
            Bs[r][bcol] = brp[bn + bcol];
        }
        __syncthreads();
        #pragma unroll
        for (int kk = 0; kk < 16; kk++) {
            float a[4], b[4];
            #pragma unroll
            for (int i = 0; i < 4; i++) a[i] = As[kk][ty + 16 * i];
            #pragma unroll
            for (int j = 0; j < 4; j++) b[j] = Bs[kk][tx + 16 * j];
            #pragma unroll
            for (int i = 0; i < 4; i++)
                #pragma unroll
                for (int j = 0; j < 4; j++) c[i][j] += a[i] * b[j];
        }
        __syncthreads();
    }
    #pragma unroll
    for (int i = 0; i < 4; i++) {
        int m = bm + ty + 16 * i;
        #pragma unroll
        for (int j = 0; j < 4; j++) {
            int n = bn + tx + 16 * j;
            float v = c[i][j] * scale;
            if (useBias) v += bias[n];
            if (useCin) v += Cin[(size_t)m * ldcin + n];
            if (useLeaky) v = v >= 0.f ? v : slope * v;
            Cout[(size_t)m * ldcout + n] = v;
        }
    }
}

// ---------------- final score: dot(h2[p], W3) + b3 ----------------
__global__ void k_score(const float* __restrict__ h2, const float* __restrict__ W3,
                        const float* __restrict__ b3, float* __restrict__ out) {
    int p = blockIdx.x;
    int lane = threadIdx.x;
    const float* r = h2 + (size_t)p * 128;
    float s = r[lane] * W3[lane] + r[lane + 64] * W3[lane + 64];
    for (int o = 32; o; o >>= 1) s += __shfl_down(s, o);
    if (lane == 0) out[p] = s + b3[0];
}

extern "C" void kernel_launch(void* const* d_in, const int* in_sizes, int n_in,
                              void* d_out, int out_size, void* d_ws, size_t ws_size,
                              hipStream_t stream) {
    const float* x_skill = (const float*)d_in[0];
    const float* x_job   = (const float*)d_in[1];
    const float* x_resume= (const float*)d_in[2];
    const float* W_rel   = (const float*)d_in[3];
    const float* b_rel   = (const float*)d_in[4];
    const float* W_root  = (const float*)d_in[5];
    const float* W_gs    = (const float*)d_in[6];
    const float* W_gd    = (const float*)d_in[7];
    const float* att_s   = (const float*)d_in[8];
    const float* att_d   = (const float*)d_in[9];
    const float* b_gat   = (const float*)d_in[10];
    const float* W1      = (const float*)d_in[11];
    const float* b1      = (const float*)d_in[12];
    const float* W2      = (const float*)d_in[13];
    const float* b2      = (const float*)d_in[14];
    const float* W3      = (const float*)d_in[15];
    const float* b3      = (const float*)d_in[16];
    const int* esj = (const int*)d_in[17];
    const int* edj = (const int*)d_in[18];
    const int* esr = (const int*)d_in[19];
    const int* edr = (const int*)d_in[20];

    const int NS = in_sizes[0] / D_;
    const int NP = in_sizes[1] / D_;
    const int EJ = in_sizes[17];
    const int ER = in_sizes[19];

    float* score = (float*)d_out;
    float* alpha = score + NP;  // [ER, H] original edge order

    char* ws = (char*)d_ws;
    size_t off = 0;
    auto alloc = [&](size_t bytes) -> void* {
        void* p = ws + off;
        off = (off + bytes + 255) & ~(size_t)255;
        return p;
    };

    int* cnt_j  = (int*)alloc((size_t)4 * NP * sizeof(int));  // cnt_j|fill_j|cnt_r|fill_r
    int* fill_j = cnt_j + NP;
    int* cnt_r  = cnt_j + 2 * NP;
    int* fill_r = cnt_j + 3 * NP;
    int* off_j  = (int*)alloc((size_t)(NP + 1) * sizeof(int));
    int* off_r  = (int*)alloc((size_t)(NP + 1) * sizeof(int));
    int* sid_j  = (int*)alloc((size_t)EJ * sizeof(int));
    int* sid_r  = (int*)alloc((size_t)ER * sizeof(int));
    float* Vsrc = (float*)alloc((size_t)D_ * H_ * 4);
    float* Vdst = (float*)alloc((size_t)D_ * H_ * 4);
    float* a_src= (float*)alloc((size_t)NS * H_ * 4);
    float* a_dst= (float*)alloc((size_t)NP * H_ * 4);
    float* agg  = (float*)alloc((size_t)NP * D_ * 4);
    float* aggatt=(float*)alloc((size_t)NP * H_ * D_ * 4);
    float* h_job= (float*)alloc((size_t)NP * D_ * 4);
    float* hcat = (float*)alloc((size_t)NP * 2 * D_ * 4);
    float* h1   = (float*)alloc((size_t)NP * 512 * 4);
    float* h2   = (float*)alloc((size_t)NP * 128 * 4);

    hipMemsetAsync(cnt_j, 0, (size_t)4 * NP * sizeof(int), stream);

    k_vmat<<<2 * D_ * H_, 256, 0, stream>>>(W_gs, W_gd, att_s, att_d, Vsrc, Vdst);
    k_a<<<NS, 256, 0, stream>>>(x_skill, Vsrc, a_src, NS);
    k_a<<<NP, 256, 0, stream>>>(x_resume, Vdst, a_dst, NP);

    int egrid = (EJ + ER + 255) / 256;
    k_count<<<egrid, 256, 0, stream>>>(edj, EJ, edr, ER, cnt_j, cnt_r);
    k_scan<<<2, 64, 0, stream>>>(cnt_j, off_j, cnt_r, off_r, NP);
    k_scatter<<<egrid, 256, 0, stream>>>(edj, EJ, edr, ER, off_j, fill_j, sid_j, off_r, fill_r, sid_r);

    k_agg<<<NP, 256, 0, stream>>>(x_skill, esj, sid_j, cnt_j, off_j, agg);
    k_softmax<<<NP, 64, 0, stream>>>(a_src, a_dst, esr, sid_r, cnt_r, off_r, alpha);
    k_aggatt<<<NP, 256, 0, stream>>>(x_skill, alpha, esr, sid_r, cnt_r, off_r, aggatt);

    // h_job = agg @ W_rel + b_rel
    gemm64<0><<<dim3(D_ / 64, NP / 64), 256, 0, stream>>>(
        agg, D_, W_rel, D_, nullptr, 0, h_job, D_, b_rel, 1.f, 0.f, D_, 0, 1, 0);
    // hcat[:, :D] = leaky(x_job @ W_root + h_job)
    gemm64<0><<<dim3(D_ / 64, NP / 64), 256, 0, stream>>>(
        x_job, D_, W_root, D_, h_job, D_, hcat, 2 * D_, nullptr, 1.f, 0.01f, D_, 1, 0, 1);
    // hcat[:, D:] = leaky( (1/H) * agg_att @ W_stack + b_gat )
    gemm64<1><<<dim3(D_ / 64, NP / 64), 256, 0, stream>>>(
        aggatt, H_ * D_, W_gs, 0, nullptr, 0, hcat + D_, 2 * D_, b_gat, 1.f / H_, 0.01f, H_ * D_, 0, 1, 1);
    // h1 = leaky(hcat @ W1 + b1)
    gemm64<0><<<dim3(512 / 64, NP / 64), 256, 0, stream>>>(
        hcat, 2 * D_, W1, 512, nullptr, 0, h1, 512, b1, 1.f, 0.01f, 2 * D_, 0, 1, 1);
    // h2 = leaky(h1 @ W2 + b2)
    gemm64<0><<<dim3(128 / 64, NP / 64), 256, 0, stream>>>(
        h1, 512, W2, 128, nullptr, 0, h2, 128, b2, 1.f, 0.01f, 512, 0, 1, 1);

    k_score<<<NP, 64, 0, stream>>>(h2, W3, b3, score);
}

// Round 2
// 748.402 us; speedup vs baseline: 3.2836x; 3.2836x over previous
//
#include <hip/hip_runtime.h>

#define D_ 1536
#define H_ 8

typedef __attribute__((ext_vector_type(8))) short bf16x8;
typedef __attribute__((ext_vector_type(4))) float f32x4;

__device__ __forceinline__ unsigned short f2bf(float f) {
    unsigned u = __builtin_bit_cast(unsigned, f);
    unsigned r = (u + 0x7fffu + ((u >> 16) & 1u)) >> 16;
    return (unsigned short)r;
}

__device__ __forceinline__ void gload16(const void* g, void* l) {
    __builtin_amdgcn_global_load_lds((const __attribute__((address_space(1))) void*)g,
                                     (__attribute__((address_space(3))) void*)l, 16, 0, 0);
}

// ---------------- V_src / V_dst: V[d,h] = sum_d2 W[d, h*D+d2] * att[h,d2] ----------------
__global__ __launch_bounds__(256) void k_vmat(const float* __restrict__ Wsrc,
                                              const float* __restrict__ Wdst,
                                              const float* __restrict__ att_s,
                                              const float* __restrict__ att_d,
                                              float* __restrict__ Vsrc,
                                              float* __restrict__ Vdst) {
    int id = blockIdx.x;
    int sel = id >= (D_ * H_);
    int idx = sel ? id - D_ * H_ : id;
    int d = idx >> 3, h = idx & 7;
    const float* W = (sel ? Wdst : Wsrc) + (size_t)d * (H_ * D_) + (size_t)h * D_;
    const float* at = (sel ? att_d : att_s) + (size_t)h * D_;
    float s = 0.f;
    for (int i = threadIdx.x; i < D_; i += 256) s += W[i] * at[i];
    for (int o = 32; o; o >>= 1) s += __shfl_down(s, o);
    __shared__ float red[4];
    if ((threadIdx.x & 63) == 0) red[threadIdx.x >> 6] = s;
    __syncthreads();
    if (threadIdx.x == 0) (sel ? Vdst : Vsrc)[d * H_ + h] = red[0] + red[1] + red[2] + red[3];
}

// ---------------- a = x @ V  ([N,D] x [D,H] -> [N,H]) ----------------
__global__ __launch_bounds__(256) void k_a(const float* __restrict__ x,
                                           const float* __restrict__ V,
                                           float* __restrict__ out, int N) {
    int n = blockIdx.x;
    if (n >= N) return;
    float part[H_] = {};
    const float* xr = x + (size_t)n * D_;
    #pragma unroll
    for (int j = 0; j < 6; j++) {
        int d = threadIdx.x + j * 256;
        float xv = xr[d];
        const float* vp = V + d * H_;
        #pragma unroll
        for (int h = 0; h < H_; h++) part[h] += xv * vp[h];
    }
    __shared__ float red[4][H_];
    int lane = threadIdx.x & 63, w = threadIdx.x >> 6;
    #pragma unroll
    for (int h = 0; h < H_; h++) {
        float v = part[h];
        for (int o = 32; o; o >>= 1) v += __shfl_down(v, o);
        if (lane == 0) red[w][h] = v;
    }
    __syncthreads();
    if (threadIdx.x < H_)
        out[(size_t)n * H_ + threadIdx.x] =
            red[0][threadIdx.x] + red[1][threadIdx.x] + red[2][threadIdx.x] + red[3][threadIdx.x];
}

// ---------------- edge counting sort ----------------
__global__ void k_count(const int* __restrict__ dj, int ej, const int* __restrict__ dr, int er,
                        int* cnt_j, int* cnt_r) {
    int i = blockIdx.x * blockDim.x + threadIdx.x;
    if (i < ej) atomicAdd(&cnt_j[dj[i]], 1);
    else if (i < ej + er) atomicAdd(&cnt_r[dr[i - ej]], 1);
}

__global__ void k_scan(const int* __restrict__ cnt_j, int* off_j,
                       const int* __restrict__ cnt_r, int* off_r, int NP) {
    const int* cnt = blockIdx.x ? cnt_r : cnt_j;
    int* off = blockIdx.x ? off_r : off_j;
    int lane = threadIdx.x;
    int chunk = (NP + 63) / 64;
    int base = lane * chunk;
    int sum = 0;
    for (int i = 0; i < chunk; i++) { int idx = base + i; if (idx < NP) sum += cnt[idx]; }
    int incl = sum;
    for (int o = 1; o < 64; o <<= 1) { int t = __shfl_up(incl, o); if (lane >= o) incl += t; }
    int run = incl - sum;
    for (int i = 0; i < chunk; i++) { int idx = base + i; if (idx < NP) { off[idx] = run; run += cnt[idx]; } }
    if (lane == 63) off[NP] = run;
}

__global__ void k_scatter(const int* __restrict__ dj, int ej, const int* __restrict__ dr, int er,
                          const int* __restrict__ off_j, int* fill_j, int* sid_j,
                          const int* __restrict__ off_r, int* fill_r, int* sid_r) {
    int i = blockIdx.x * blockDim.x + threadIdx.x;
    if (i < ej) {
        int p = dj[i];
        int slot = atomicAdd(&fill_j[p], 1);
        sid_j[off_j[p] + slot] = i;
    } else if (i < ej + er) {
        int e = i - ej;
        int p = dr[e];
        int slot = atomicAdd(&fill_r[p], 1);
        sid_r[off_r[p] + slot] = e;
    }
}

// ---------------- GraphConv aggregate -> bf16 into cat_in[:, 0:D] ----------------
__global__ __launch_bounds__(256) void k_agg(const float* __restrict__ x, const int* __restrict__ src,
                                             const int* __restrict__ sid, const int* __restrict__ cnt,
                                             const int* __restrict__ off, unsigned short* __restrict__ cat_in) {
    int p = blockIdx.x;
    int n = cnt[p], o = off[p];
    float acc[6] = {};
    for (int i = 0; i < n; i++) {
        int e = sid[o + i];
        const float* xr = x + (size_t)src[e] * D_ + threadIdx.x;
        #pragma unroll
        for (int j = 0; j < 6; j++) acc[j] += xr[j * 256];
    }
    unsigned short* orow = cat_in + (size_t)p * (2 * D_) + threadIdx.x;
    #pragma unroll
    for (int j = 0; j < 6; j++) orow[j * 256] = f2bf(acc[j]);
}

// ---------------- x_job -> bf16 into cat_in[:, D:2D] ----------------
__global__ __launch_bounds__(256) void k_xjob(const float* __restrict__ x_job,
                                              unsigned short* __restrict__ cat_in) {
    int p = blockIdx.x;
    const float* xr = x_job + (size_t)p * D_ + threadIdx.x;
    unsigned short* orow = cat_in + (size_t)p * (2 * D_) + D_ + threadIdx.x;
    #pragma unroll
    for (int j = 0; j < 6; j++) orow[j * 256] = f2bf(xr[j * 256]);
}

// ---------------- GAT segment softmax -> alpha (original edge order, fp32) ----------------
__global__ void k_softmax(const float* __restrict__ a_src, const float* __restrict__ a_dst,
                          const int* __restrict__ src, const int* __restrict__ sid,
                          const int* __restrict__ cnt, const int* __restrict__ off,
                          float* __restrict__ alpha_out) {
    int p = blockIdx.x;
    int n = cnt[p], o = off[p];
    if (n == 0) return;
    int lane = threadIdx.x;
    #pragma unroll 1
    for (int h = 0; h < H_; h++) {
        float ad = a_dst[(size_t)p * H_ + h];
        float m = -3.4e38f;
        for (int i = lane; i < n; i += 64) {
            int e = sid[o + i];
            float v = a_src[(size_t)src[e] * H_ + h] + ad;
            v = v >= 0.f ? v : 0.2f * v;
            m = fmaxf(m, v);
        }
        for (int o2 = 32; o2; o2 >>= 1) m = fmaxf(m, __shfl_xor(m, o2));
        float s = 0.f;
        for (int i = lane; i < n; i += 64) {
            int e = sid[o + i];
            float v = a_src[(size_t)src[e] * H_ + h] + ad;
            v = v >= 0.f ? v : 0.2f * v;
            s += expf(v - m);
        }
        for (int o2 = 32; o2; o2 >>= 1) s += __shfl_xor(s, o2);
        float inv = 1.f / (s + 1e-16f);
        for (int i = lane; i < n; i += 64) {
            int e = sid[o + i];
            float v = a_src[(size_t)src[e] * H_ + h] + ad;
            v = v >= 0.f ? v : 0.2f * v;
            alpha_out[(size_t)e * H_ + h] = expf(v - m) * inv;
        }
    }
}

// ---------------- attention-weighted aggregate (input space) -> bf16 ----------------
__global__ __launch_bounds__(256) void k_aggatt(const float* __restrict__ x,
                                                const float* __restrict__ alpha,
                                                const int* __restrict__ src, const int* __restrict__ sid,
                                                const int* __restrict__ cnt, const int* __restrict__ off,
                                                unsigned short* __restrict__ aggatt) {
    int p = blockIdx.x;
    int n = cnt[p], o = off[p];
    float acc[H_][6] = {};
    for (int i = 0; i < n; i++) {
        int e = sid[o + i];
        int s = src[e];
        const float* ap = alpha + (size_t)e * H_;
        float al[H_];
        #pragma unroll
        for (int h = 0; h < H_; h++) al[h] = ap[h];
        const float* xr = x + (size_t)s * D_ + threadIdx.x;
        float xv[6];
        #pragma unroll
        for (int j = 0; j < 6; j++) xv[j] = xr[j * 256];
        #pragma unroll
        for (int h = 0; h < H_; h++)
            #pragma unroll
            for (int j = 0; j < 6; j++) acc[h][j] += al[h] * xv[j];
    }
    unsigned short* orow = aggatt + (size_t)p * (H_ * D_) + threadIdx.x;
    #pragma unroll
    for (int h = 0; h < H_; h++)
        #pragma unroll
        for (int j = 0; j < 6; j++) orow[h * D_ + j * 256] = f2bf(acc[h][j]);
}

// ---------------- fp32 [K][N] -> bf16 [N][K] transpose (GATB: permuted stacked weights) ----------
template <int GATB>
__global__ __launch_bounds__(256) void k_tr(const float* __restrict__ in, int ldin,
                                            unsigned short* __restrict__ out, int ldout) {
    __shared__ float t[64][65];
    int k0 = blockIdx.y * 64, n0 = blockIdx.x * 64;
    int tx = threadIdx.x & 63, ty = threadIdx.x >> 6;
    #pragma unroll
    for (int i = 0; i < 16; i++) {
        int k = k0 + ty + i * 4;
        const float* rp;
        if (GATB) {
            int d2 = k % D_, h = k / D_;
            rp = in + (size_t)d2 * (H_ * D_) + (size_t)h * D_;
        } else {
            rp = in + (size_t)k * ldin;
        }
        t[ty + i * 4][tx] = rp[n0 + tx];
    }
    __syncthreads();
    #pragma unroll
    for (int i = 0; i < 16; i++) {
        int n = n0 + ty + i * 4;
        out[(size_t)n * ldout + k0 + tx] = f2bf(t[tx][ty + i * 4]);
    }
}

// ---------------- bf16 MFMA GEMM: C[m,n] = epi(scale * sum_k A[m,k]*BT[n,k] + bias[n]) --------
// 128x128 tile, 4 waves (2x2), BK=32, global_load_lds width-16 staging.
template <int OUT_BF16>
__global__ __launch_bounds__(256) void gemm_mfma(const unsigned short* __restrict__ A, int lda,
                                                 const unsigned short* __restrict__ BT, int ldb,
                                                 void* __restrict__ Cout, int ldc,
                                                 const float* __restrict__ bias,
                                                 float scale, int K, int useLeaky) {
    __shared__ unsigned short As[128 * 32];
    __shared__ unsigned short Bs[128 * 32];
    int tid = threadIdx.x;
    int lane = tid & 63, wid = tid >> 6;
    int bm = blockIdx.y * 128, bn = blockIdx.x * 128;
    int wr = wid >> 1, wc = wid & 1;
    int srow = lane >> 2;            // row within 16-row chunk
    int skc = (lane & 3) * 8;        // k element offset within 32
    int fr = lane & 15, kg = (lane >> 4) * 8;

    f32x4 acc[4][4] = {};

    for (int k0 = 0; k0 < K; k0 += 32) {
        #pragma unroll
        for (int i = 0; i < 2; i++) {
            int chunk = wid * 2 + i;                 // 0..7
            int r = chunk * 16 + srow;               // 0..127
            gload16(A + (size_t)(bm + r) * lda + k0 + skc, As + chunk * 512);
            gload16(BT + (size_t)(bn + r) * ldb + k0 + skc, Bs + chunk * 512);
        }
        __syncthreads();
        bf16x8 a[4], b[4];
        #pragma unroll
        for (int mi = 0; mi < 4; mi++)
            a[mi] = *(const bf16x8*)(As + (wr * 64 + mi * 16 + fr) * 32 + kg);
        #pragma unroll
        for (int ni = 0; ni < 4; ni++)
            b[ni] = *(const bf16x8*)(Bs + (wc * 64 + ni * 16 + fr) * 32 + kg);
        #pragma unroll
        for (int mi = 0; mi < 4; mi++)
            #pragma unroll
            for (int ni = 0; ni < 4; ni++)
                acc[mi][ni] = __builtin_amdgcn_mfma_f32_16x16x32_bf16(a[mi], b[ni], acc[mi][ni], 0, 0, 0);
        __syncthreads();
    }

    #pragma unroll
    for (int mi = 0; mi < 4; mi++) {
        int r0 = bm + wr * 64 + mi * 16 + (lane >> 4) * 4;
        #pragma unroll
        for (int ni = 0; ni < 4; ni++) {
            int c = bn + wc * 64 + ni * 16 + (lane & 15);
            float bv = bias[c];
            #pragma unroll
            for (int j = 0; j < 4; j++) {
                float v = acc[mi][ni][j] * scale + bv;
                if (useLeaky) v = v >= 0.f ? v : 0.01f * v;
                if (OUT_BF16)
                    ((unsigned short*)Cout)[(size_t)(r0 + j) * ldc + c] = f2bf(v);
                else
                    ((float*)Cout)[(size_t)(r0 + j) * ldc + c] = v;
            }
        }
    }
}

// ---------------- generic 64x64 fp32 GEMM (small tails) ----------------
__global__ __launch_bounds__(256) void gemm64(const float* __restrict__ A, int lda,
                                              const float* __restrict__ B, int ldb,
                                              float* __restrict__ Cout, int ldcout,
                                              const float* __restrict__ bias,
                                              float slope, int K) {
    __shared__ float As[16][65];
    __shared__ float Bs[16][64];
    int tid = threadIdx.x;
    int bm = blockIdx.y * 64, bn = blockIdx.x * 64;
    int tx = tid & 15, ty = tid >> 4;
    int acol = tid & 15, arow = tid >> 4;
    int bcol = tid & 63, brow = tid >> 6;
    float c[4][4] = {};
    for (int k0 = 0; k0 < K; k0 += 16) {
        #pragma unroll
        for (int i = 0; i < 4; i++) {
            int r = arow + 16 * i;
            As[acol][r] = A[(size_t)(bm + r) * lda + k0 + acol];
        }
        #pragma unroll
        for (int i = 0; i < 4; i++) {
            int r = brow + 4 * i;
            Bs[r][bcol] = B[(size_t)(k0 + r) * ldb + bn + bcol];
        }
        __syncthreads();
        #pragma unroll
        for (int kk = 0; kk < 16; kk++) {
            float a[4], b[4];
            #pragma unroll
            for (int i = 0; i < 4; i++) a[i] = As[kk][ty + 16 * i];
            #pragma unroll
            for (int j = 0; j < 4; j++) b[j] = Bs[kk][tx + 16 * j];
            #pragma unroll
            for (int i = 0; i < 4; i++)
                #pragma unroll
                for (int j = 0; j < 4; j++) c[i][j] += a[i] * b[j];
        }
        __syncthreads();
    }
    #pragma unroll
    for (int i = 0; i < 4; i++) {
        int m = bm + ty + 16 * i;
        #pragma unroll
        for (int j = 0; j < 4; j++) {
            int n = bn + tx + 16 * j;
            float v = c[i][j] + bias[n];
            v = v >= 0.f ? v : slope * v;
            Cout[(size_t)m * ldcout + n] = v;
        }
    }
}

// ---------------- final score: dot(h2[p], W3) + b3 ----------------
__global__ void k_score(const float* __restrict__ h2, const float* __restrict__ W3,
                        const float* __restrict__ b3, float* __restrict__ out) {
    int p = blockIdx.x;
    int lane = threadIdx.x;
    const float* r = h2 + (size_t)p * 128;
    float s = r[lane] * W3[lane] + r[lane + 64] * W3[lane + 64];
    for (int o = 32; o; o >>= 1) s += __shfl_down(s, o);
    if (lane == 0) out[p] = s + b3[0];
}

extern "C" void kernel_launch(void* const* d_in, const int* in_sizes, int n_in,
                              void* d_out, int out_size, void* d_ws, size_t ws_size,
                              hipStream_t stream) {
    const float* x_skill = (const float*)d_in[0];
    const float* x_job   = (const float*)d_in[1];
    const float* x_resume= (const float*)d_in[2];
    const float* W_rel   = (const float*)d_in[3];
    const float* b_rel   = (const float*)d_in[4];
    const float* W_root  = (const float*)d_in[5];
    const float* W_gs    = (const float*)d_in[6];
    const float* W_gd    = (const float*)d_in[7];
    const float* att_s   = (const float*)d_in[8];
    const float* att_d   = (const float*)d_in[9];
    const float* b_gat   = (const float*)d_in[10];
    const float* W1      = (const float*)d_in[11];
    const float* b1      = (const float*)d_in[12];
    const float* W2      = (const float*)d_in[13];
    const float* b2      = (const float*)d_in[14];
    const float* W3      = (const float*)d_in[15];
    const float* b3      = (const float*)d_in[16];
    const int* esj = (const int*)d_in[17];
    const int* edj = (const int*)d_in[18];
    const int* esr = (const int*)d_in[19];
    const int* edr = (const int*)d_in[20];

    const int NS = in_sizes[0] / D_;
    const int NP = in_sizes[1] / D_;
    const int EJ = in_sizes[17];
    const int ER = in_sizes[19];

    float* score = (float*)d_out;
    float* alpha = score + NP;  // [ER, H] original edge order

    char* ws = (char*)d_ws;
    size_t off = 0;
    auto alloc = [&](size_t bytes) -> void* {
        void* p = ws + off;
        off = (off + bytes + 255) & ~(size_t)255;
        return p;
    };

    int* cnt_j  = (int*)alloc((size_t)4 * NP * sizeof(int));  // cnt_j|fill_j|cnt_r|fill_r
    int* fill_j = cnt_j + NP;
    int* cnt_r  = cnt_j + 2 * NP;
    int* fill_r = cnt_j + 3 * NP;
    int* off_j  = (int*)alloc((size_t)(NP + 1) * sizeof(int));
    int* off_r  = (int*)alloc((size_t)(NP + 1) * sizeof(int));
    int* sid_j  = (int*)alloc((size_t)EJ * sizeof(int));
    int* sid_r  = (int*)alloc((size_t)ER * sizeof(int));
    float* Vsrc = (float*)alloc((size_t)D_ * H_ * 4);
    float* Vdst = (float*)alloc((size_t)D_ * H_ * 4);
    float* a_src= (float*)alloc((size_t)NS * H_ * 4);
    float* a_dst= (float*)alloc((size_t)NP * H_ * 4);
    unsigned short* cat_in = (unsigned short*)alloc((size_t)NP * 2 * D_ * 2);      // [NP, 2D] bf16
    unsigned short* aggatt = (unsigned short*)alloc((size_t)NP * H_ * D_ * 2);     // [NP, H*D] bf16
    unsigned short* BT1    = (unsigned short*)alloc((size_t)D_ * 2 * D_ * 2);      // [D, 2D] bf16
    unsigned short* BTg    = (unsigned short*)alloc((size_t)D_ * H_ * D_ * 2);     // [D, H*D] bf16
    unsigned short* BTw1   = (unsigned short*)alloc((size_t)512 * 2 * D_ * 2);     // [512, 2D] bf16
    unsigned short* hcat   = (unsigned short*)alloc((size_t)NP * 2 * D_ * 2);      // [NP, 2D] bf16
    float* h1   = (float*)alloc((size_t)NP * 512 * 4);
    float* h2   = (float*)alloc((size_t)NP * 128 * 4);

    hipMemsetAsync(cnt_j, 0, (size_t)4 * NP * sizeof(int), stream);

    // weight repacks (fp32 [K][N] -> bf16 [N][K])
    k_tr<0><<<dim3(D_ / 64, D_ / 64), 256, 0, stream>>>(W_rel, D_, BT1, 2 * D_);
    k_tr<0><<<dim3(D_ / 64, D_ / 64), 256, 0, stream>>>(W_root, D_, BT1 + D_, 2 * D_);
    k_tr<1><<<dim3(D_ / 64, (H_ * D_) / 64), 256, 0, stream>>>(W_gs, 0, BTg, H_ * D_);
    k_tr<0><<<dim3(512 / 64, (2 * D_) / 64), 256, 0, stream>>>(W1, 512, BTw1, 2 * D_);

    k_vmat<<<2 * D_ * H_, 256, 0, stream>>>(W_gs, W_gd, att_s, att_d, Vsrc, Vdst);
    k_a<<<NS, 256, 0, stream>>>(x_skill, Vsrc, a_src, NS);
    k_a<<<NP, 256, 0, stream>>>(x_resume, Vdst, a_dst, NP);

    int egrid = (EJ + ER + 255) / 256;
    k_count<<<egrid, 256, 0, stream>>>(edj, EJ, edr, ER, cnt_j, cnt_r);
    k_scan<<<2, 64, 0, stream>>>(cnt_j, off_j, cnt_r, off_r, NP);
    k_scatter<<<egrid, 256, 0, stream>>>(edj, EJ, edr, ER, off_j, fill_j, sid_j, off_r, fill_r, sid_r);

    k_agg<<<NP, 256, 0, stream>>>(x_skill, esj, sid_j, cnt_j, off_j, cat_in);
    k_xjob<<<NP, 256, 0, stream>>>(x_job, cat_in);
    k_softmax<<<NP, 64, 0, stream>>>(a_src, a_dst, esr, sid_r, cnt_r, off_r, alpha);
    k_aggatt<<<NP, 256, 0, stream>>>(x_skill, alpha, esr, sid_r, cnt_r, off_r, aggatt);

    // hcat[:, :D] = leaky([agg|x_job] @ [W_rel;W_root] + b_rel)   K=3072
    gemm_mfma<1><<<dim3(D_ / 128, NP / 128), 256, 0, stream>>>(
        cat_in, 2 * D_, BT1, 2 * D_, hcat, 2 * D_, b_rel, 1.f, 2 * D_, 1);
    // hcat[:, D:] = leaky((1/H) * aggatt @ Wstack + b_gat)        K=12288
    gemm_mfma<1><<<dim3(D_ / 128, NP / 128), 256, 0, stream>>>(
        aggatt, H_ * D_, BTg, H_ * D_, hcat + D_, 2 * D_, b_gat, 1.f / H_, H_ * D_, 1);
    // h1 = leaky(hcat @ W1 + b1)  (fp32 out)                      K=3072
    gemm_mfma<0><<<dim3(512 / 128, NP / 128), 256, 0, stream>>>(
        hcat, 2 * D_, BTw1, 2 * D_, h1, 512, b1, 1.f, 2 * D_, 1);
    // h2 = leaky(h1 @ W2 + b2)  fp32
    gemm64<<<dim3(128 / 64, NP / 64), 256, 0, stream>>>(
        h1, 512, W2, 128, h2, 128, b2, 0.01f, 512);

    k_score<<<NP, 64, 0, stream>>>(h2, W3, b3, score);
}

// Round 3
// 516.418 us; speedup vs baseline: 4.7587x; 1.4492x over previous
//
#include <hip/hip_runtime.h>

#define D_ 1536
#define H_ 8

typedef __attribute__((ext_vector_type(8))) short bf16x8;
typedef __attribute__((ext_vector_type(4))) float f32x4;

__device__ __forceinline__ unsigned short f2bf(float f) {
    unsigned u = __builtin_bit_cast(unsigned, f);
    unsigned r = (u + 0x7fffu + ((u >> 16) & 1u)) >> 16;
    return (unsigned short)r;
}

__device__ __forceinline__ void gload16(const void* g, void* l) {
    __builtin_amdgcn_global_load_lds((const __attribute__((address_space(1))) void*)g,
                                     (__attribute__((address_space(3))) void*)l, 16, 0, 0);
}

// ---------------- V_src / V_dst: V[d,h] = sum_d2 W[d, h*D+d2] * att[h,d2] ----------------
__global__ __launch_bounds__(256) void k_vmat(const float* __restrict__ Wsrc,
                                              const float* __restrict__ Wdst,
                                              const float* __restrict__ att_s,
                                              const float* __restrict__ att_d,
                                              float* __restrict__ Vsrc,
                                              float* __restrict__ Vdst) {
    int id = blockIdx.x;
    int sel = id >= (D_ * H_);
    int idx = sel ? id - D_ * H_ : id;
    int d = idx >> 3, h = idx & 7;
    const float* W = (sel ? Wdst : Wsrc) + (size_t)d * (H_ * D_) + (size_t)h * D_;
    const float* at = (sel ? att_d : att_s) + (size_t)h * D_;
    float s = 0.f;
    for (int i = threadIdx.x; i < D_; i += 256) s += W[i] * at[i];
    for (int o = 32; o; o >>= 1) s += __shfl_down(s, o);
    __shared__ float red[4];
    if ((threadIdx.x & 63) == 0) red[threadIdx.x >> 6] = s;
    __syncthreads();
    if (threadIdx.x == 0) (sel ? Vdst : Vsrc)[d * H_ + h] = red[0] + red[1] + red[2] + red[3];
}

// ---------------- a = x @ V  ([N,D] x [D,H] -> [N,H]) ----------------
__global__ __launch_bounds__(256) void k_a(const float* __restrict__ x,
                                           const float* __restrict__ V,
                                           float* __restrict__ out, int N) {
    int n = blockIdx.x;
    if (n >= N) return;
    float part[H_] = {};
    const float* xr = x + (size_t)n * D_;
    #pragma unroll
    for (int j = 0; j < 6; j++) {
        int d = threadIdx.x + j * 256;
        float xv = xr[d];
        const float* vp = V + d * H_;
        #pragma unroll
        for (int h = 0; h < H_; h++) part[h] += xv * vp[h];
    }
    __shared__ float red[4][H_];
    int lane = threadIdx.x & 63, w = threadIdx.x >> 6;
    #pragma unroll
    for (int h = 0; h < H_; h++) {
        float v = part[h];
        for (int o = 32; o; o >>= 1) v += __shfl_down(v, o);
        if (lane == 0) red[w][h] = v;
    }
    __syncthreads();
    if (threadIdx.x < H_)
        out[(size_t)n * H_ + threadIdx.x] =
            red[0][threadIdx.x] + red[1][threadIdx.x] + red[2][threadIdx.x] + red[3][threadIdx.x];
}

// ---------------- edge counting sort ----------------
__global__ void k_count(const int* __restrict__ dj, int ej, const int* __restrict__ dr, int er,
                        int* cnt_j, int* cnt_r) {
    int i = blockIdx.x * blockDim.x + threadIdx.x;
    if (i < ej) atomicAdd(&cnt_j[dj[i]], 1);
    else if (i < ej + er) atomicAdd(&cnt_r[dr[i - ej]], 1);
}

__global__ void k_scan(const int* __restrict__ cnt_j, int* off_j,
                       const int* __restrict__ cnt_r, int* off_r, int NP) {
    const int* cnt = blockIdx.x ? cnt_r : cnt_j;
    int* off = blockIdx.x ? off_r : off_j;
    int lane = threadIdx.x;
    int chunk = (NP + 63) / 64;
    int base = lane * chunk;
    int sum = 0;
    for (int i = 0; i < chunk; i++) { int idx = base + i; if (idx < NP) sum += cnt[idx]; }
    int incl = sum;
    for (int o = 1; o < 64; o <<= 1) { int t = __shfl_up(incl, o); if (lane >= o) incl += t; }
    int run = incl - sum;
    for (int i = 0; i < chunk; i++) { int idx = base + i; if (idx < NP) { off[idx] = run; run += cnt[idx]; } }
    if (lane == 63) off[NP] = run;
}

__global__ void k_scatter(const int* __restrict__ dj, int ej, const int* __restrict__ dr, int er,
                          const int* __restrict__ off_j, int* fill_j, int* sid_j,
                          const int* __restrict__ off_r, int* fill_r, int* sid_r) {
    int i = blockIdx.x * blockDim.x + threadIdx.x;
    if (i < ej) {
        int p = dj[i];
        int slot = atomicAdd(&fill_j[p], 1);
        sid_j[off_j[p] + slot] = i;
    } else if (i < ej + er) {
        int e = i - ej;
        int p = dr[e];
        int slot = atomicAdd(&fill_r[p], 1);
        sid_r[off_r[p] + slot] = e;
    }
}

// ---------------- GraphConv aggregate -> bf16 into cat_in[:, 0:D] ----------------
__global__ __launch_bounds__(256) void k_agg(const float* __restrict__ x, const int* __restrict__ src,
                                             const int* __restrict__ sid, const int* __restrict__ cnt,
                                             const int* __restrict__ off, unsigned short* __restrict__ cat_in) {
    int p = blockIdx.x;
    int n = cnt[p], o = off[p];
    float acc[6] = {};
    for (int i = 0; i < n; i++) {
        int e = sid[o + i];
        const float* xr = x + (size_t)src[e] * D_ + threadIdx.x;
        #pragma unroll
        for (int j = 0; j < 6; j++) acc[j] += xr[j * 256];
    }
    unsigned short* orow = cat_in + (size_t)p * (2 * D_) + threadIdx.x;
    #pragma unroll
    for (int j = 0; j < 6; j++) orow[j * 256] = f2bf(acc[j]);
}

// ---------------- x_job -> bf16 into cat_in[:, D:2D] ----------------
__global__ __launch_bounds__(256) void k_xjob(const float* __restrict__ x_job,
                                              unsigned short* __restrict__ cat_in) {
    int p = blockIdx.x;
    const float* xr = x_job + (size_t)p * D_ + threadIdx.x;
    unsigned short* orow = cat_in + (size_t)p * (2 * D_) + D_ + threadIdx.x;
    #pragma unroll
    for (int j = 0; j < 6; j++) orow[j * 256] = f2bf(xr[j * 256]);
}

// ---------------- GAT segment softmax -> alpha (original edge order, fp32) ----------------
__global__ void k_softmax(const float* __restrict__ a_src, const float* __restrict__ a_dst,
                          const int* __restrict__ src, const int* __restrict__ sid,
                          const int* __restrict__ cnt, const int* __restrict__ off,
                          float* __restrict__ alpha_out) {
    int p = blockIdx.x;
    int n = cnt[p], o = off[p];
    if (n == 0) return;
    int lane = threadIdx.x;
    #pragma unroll 1
    for (int h = 0; h < H_; h++) {
        float ad = a_dst[(size_t)p * H_ + h];
        float m = -3.4e38f;
        for (int i = lane; i < n; i += 64) {
            int e = sid[o + i];
            float v = a_src[(size_t)src[e] * H_ + h] + ad;
            v = v >= 0.f ? v : 0.2f * v;
            m = fmaxf(m, v);
        }
        for (int o2 = 32; o2; o2 >>= 1) m = fmaxf(m, __shfl_xor(m, o2));
        float s = 0.f;
        for (int i = lane; i < n; i += 64) {
            int e = sid[o + i];
            float v = a_src[(size_t)src[e] * H_ + h] + ad;
            v = v >= 0.f ? v : 0.2f * v;
            s += expf(v - m);
        }
        for (int o2 = 32; o2; o2 >>= 1) s += __shfl_xor(s, o2);
        float inv = 1.f / (s + 1e-16f);
        for (int i = lane; i < n; i += 64) {
            int e = sid[o + i];
            float v = a_src[(size_t)src[e] * H_ + h] + ad;
            v = v >= 0.f ? v : 0.2f * v;
            alpha_out[(size_t)e * H_ + h] = expf(v - m) * inv;
        }
    }
}

// ---------------- attention-weighted aggregate (input space) -> bf16 ----------------
__global__ __launch_bounds__(256) void k_aggatt(const float* __restrict__ x,
                                                const float* __restrict__ alpha,
                                                const int* __restrict__ src, const int* __restrict__ sid,
                                                const int* __restrict__ cnt, const int* __restrict__ off,
                                                unsigned short* __restrict__ aggatt) {
    int p = blockIdx.x;
    int n = cnt[p], o = off[p];
    float acc[H_][6] = {};
    for (int i = 0; i < n; i++) {
        int e = sid[o + i];
        int s = src[e];
        const float* ap = alpha + (size_t)e * H_;
        float al[H_];
        #pragma unroll
        for (int h = 0; h < H_; h++) al[h] = ap[h];
        const float* xr = x + (size_t)s * D_ + threadIdx.x;
        float xv[6];
        #pragma unroll
        for (int j = 0; j < 6; j++) xv[j] = xr[j * 256];
        #pragma unroll
        for (int h = 0; h < H_; h++)
            #pragma unroll
            for (int j = 0; j < 6; j++) acc[h][j] += al[h] * xv[j];
    }
    unsigned short* orow = aggatt + (size_t)p * (H_ * D_) + threadIdx.x;
    #pragma unroll
    for (int h = 0; h < H_; h++)
        #pragma unroll
        for (int j = 0; j < 6; j++) orow[h * D_ + j * 256] = f2bf(acc[h][j]);
}

// ---------------- fp32 [K][N] -> bf16 [N][K] transpose (GATB: permuted stacked weights) ----------
template <int GATB>
__global__ __launch_bounds__(256) void k_tr(const float* __restrict__ in, int ldin,
                                            unsigned short* __restrict__ out, int ldout) {
    __shared__ float t[64][65];
    int k0 = blockIdx.y * 64, n0 = blockIdx.x * 64;
    int tx = threadIdx.x & 63, ty = threadIdx.x >> 6;
    #pragma unroll
    for (int i = 0; i < 16; i++) {
        int k = k0 + ty + i * 4;
        const float* rp;
        if (GATB) {
            int d2 = k % D_, h = k / D_;
            rp = in + (size_t)d2 * (H_ * D_) + (size_t)h * D_;
        } else {
            rp = in + (size_t)k * ldin;
        }
        t[ty + i * 4][tx] = rp[n0 + tx];
    }
    __syncthreads();
    #pragma unroll
    for (int i = 0; i < 16; i++) {
        int n = n0 + ty + i * 4;
        out[(size_t)n * ldout + k0 + tx] = f2bf(t[tx][ty + i * 4]);
    }
}

// ---------------- bf16 MFMA GEMM, split-K, XCD-swizzled, conflict-swizzled LDS ----------------
// grid: x = N/128, y = M/128, z = splits. Partial P[z][m][n] fp32, no epilogue.
// LDS layout: row r (64B = 4 slots of 16B), stored slot sl holds global slot sl^((r>>1)&3).
__global__ __launch_bounds__(256) void gemm_mfma_sk(const unsigned short* __restrict__ A, int lda,
                                                    const unsigned short* __restrict__ BT, int ldb,
                                                    float* __restrict__ P, int N, int Kc) {
    __shared__ unsigned short As[128 * 32];
    __shared__ unsigned short Bs[128 * 32];
    int tid = threadIdx.x;
    int lane = tid & 63, wid = tid >> 6;

    // XCD-aware swizzle of flattened (x,y); nwg % 8 == 0 for all our grids
    int nwg = gridDim.x * gridDim.y;
    int bidh = blockIdx.y * gridDim.x + blockIdx.x;
    int swz = (bidh & 7) * (nwg >> 3) + (bidh >> 3);
    int bn = (swz % gridDim.x) * 128;
    int bm = (swz / gridDim.x) * 128;

    int kbase = blockIdx.z * Kc;
    int wr = wid >> 1, wc = wid & 1;
    int fr = lane & 15, g = lane >> 4;          // fragment row, k-slot group

    // staging: chunk c covers rows c*16..c*16+15; lane -> (row, stored slot)
    int srow = lane >> 2;
    int ssl = lane & 3;

    f32x4 acc[4][4] = {};

    for (int k0 = kbase; k0 < kbase + Kc; k0 += 32) {
        #pragma unroll
        for (int i = 0; i < 2; i++) {
            int c = wid * 2 + i;
            int r = c * 16 + srow;
            int sg = ssl ^ ((r >> 1) & 3);      // global slot fetched into stored slot ssl
            gload16(A + (size_t)(bm + r) * lda + k0 + sg * 8, As + c * 512);
            gload16(BT + (size_t)(bn + r) * ldb + k0 + sg * 8, Bs + c * 512);
        }
        __syncthreads();
        bf16x8 a[4], b[4];
        #pragma unroll
        for (int mi = 0; mi < 4; mi++) {
            int row = wr * 64 + mi * 16 + fr;
            a[mi] = *(const bf16x8*)(As + row * 32 + ((g ^ ((row >> 1) & 3)) * 8));
        }
        #pragma unroll
        for (int ni = 0; ni < 4; ni++) {
            int row = wc * 64 + ni * 16 + fr;
            b[ni] = *(const bf16x8*)(Bs + row * 32 + ((g ^ ((row >> 1) & 3)) * 8));
        }
        #pragma unroll
        for (int mi = 0; mi < 4; mi++)
            #pragma unroll
            for (int ni = 0; ni < 4; ni++)
                acc[mi][ni] = __builtin_amdgcn_mfma_f32_16x16x32_bf16(a[mi], b[ni], acc[mi][ni], 0, 0, 0);
        __syncthreads();
    }

    size_t MN = (size_t)N * (size_t)(gridDim.y * 128);
    float* Pz = P + (size_t)blockIdx.z * MN;
    #pragma unroll
    for (int mi = 0; mi < 4; mi++) {
        int r0 = bm + wr * 64 + mi * 16 + (lane >> 4) * 4;
        #pragma unroll
        for (int ni = 0; ni < 4; ni++) {
            int c = bn + wc * 64 + ni * 16 + (lane & 15);
            #pragma unroll
            for (int j = 0; j < 4; j++)
                Pz[(size_t)(r0 + j) * N + c] = acc[mi][ni][j];
        }
    }
}

// ---------------- split-K reduce + epilogue ----------------
template <int OUT_BF16>
__global__ __launch_bounds__(256) void k_reduce(const float* __restrict__ P, int S, int MN, int N,
                                                void* __restrict__ Cout, int ldc,
                                                const float* __restrict__ bias, float scale,
                                                int useLeaky) {
    int idx = (blockIdx.x * 256 + threadIdx.x) * 4;
    if (idx >= MN) return;
    float4 v = *(const float4*)(P + idx);
    for (int s = 1; s < S; s++) {
        float4 t = *(const float4*)(P + (size_t)s * MN + idx);
        v.x += t.x; v.y += t.y; v.z += t.z; v.w += t.w;
    }
    int m = idx / N, n = idx - m * N;
    float vv[4] = {v.x, v.y, v.z, v.w};
    #pragma unroll
    for (int j = 0; j < 4; j++) {
        float x = vv[j] * scale + bias[n + j];
        if (useLeaky) x = x >= 0.f ? x : 0.01f * x;
        if (OUT_BF16) ((unsigned short*)Cout)[(size_t)m * ldc + n + j] = f2bf(x);
        else ((float*)Cout)[(size_t)m * ldc + n + j] = x;
    }
}

// ---------------- generic 64x64 fp32 GEMM (small tail) ----------------
__global__ __launch_bounds__(256) void gemm64(const float* __restrict__ A, int lda,
                                              const float* __restrict__ B, int ldb,
                                              float* __restrict__ Cout, int ldcout,
                                              const float* __restrict__ bias,
                                              float slope, int K) {
    __shared__ float As[16][65];
    __shared__ float Bs[16][64];
    int tid = threadIdx.x;
    int bm = blockIdx.y * 64, bn = blockIdx.x * 64;
    int tx = tid & 15, ty = tid >> 4;
    int acol = tid & 15, arow = tid >> 4;
    int bcol = tid & 63, brow = tid >> 6;
    float c[4][4] = {};
    for (int k0 = 0; k0 < K; k0 += 16) {
        #pragma unroll
        for (int i = 0; i < 4; i++) {
            int r = arow + 16 * i;
            As[acol][r] = A[(size_t)(bm + r) * lda + k0 + acol];
        }
        #pragma unroll
        for (int i = 0; i < 4; i++) {
            int r = brow + 4 * i;
            Bs[r][bcol] = B[(size_t)(k0 + r) * ldb + bn + bcol];
        }
        __syncthreads();
        #pragma unroll
        for (int kk = 0; kk < 16; kk++) {
            float a[4], b[4];
            #pragma unroll
            for (int i = 0; i < 4; i++) a[i] = As[kk][ty + 16 * i];
            #pragma unroll
            for (int j = 0; j < 4; j++) b[j] = Bs[kk][tx + 16 * j];
            #pragma unroll
            for (int i = 0; i < 4; i++)
                #pragma unroll
                for (int j = 0; j < 4; j++) c[i][j] += a[i] * b[j];
        }
        __syncthreads();
    }
    #pragma unroll
    for (int i = 0; i < 4; i++) {
        int m = bm + ty + 16 * i;
        #pragma unroll
        for (int j = 0; j < 4; j++) {
            int n = bn + tx + 16 * j;
            float v = c[i][j] + bias[n];
            v = v >= 0.f ? v : slope * v;
            Cout[(size_t)m * ldcout + n] = v;
        }
    }
}

// ---------------- final score: dot(h2[p], W3) + b3 ----------------
__global__ void k_score(const float* __restrict__ h2, const float* __restrict__ W3,
                        const float* __restrict__ b3, float* __restrict__ out) {
    int p = blockIdx.x;
    int lane = threadIdx.x;
    const float* r = h2 + (size_t)p * 128;
    float s = r[lane] * W3[lane] + r[lane + 64] * W3[lane + 64];
    for (int o = 32; o; o >>= 1) s += __shfl_down(s, o);
    if (lane == 0) out[p] = s + b3[0];
}

extern "C" void kernel_launch(void* const* d_in, const int* in_sizes, int n_in,
                              void* d_out, int out_size, void* d_ws, size_t ws_size,
                              hipStream_t stream) {
    const float* x_skill = (const float*)d_in[0];
    const float* x_job   = (const float*)d_in[1];
    const float* x_resume= (const float*)d_in[2];
    const float* W_rel   = (const float*)d_in[3];
    const float* b_rel   = (const float*)d_in[4];
    const float* W_root  = (const float*)d_in[5];
    const float* W_gs    = (const float*)d_in[6];
    const float* W_gd    = (const float*)d_in[7];
    const float* att_s   = (const float*)d_in[8];
    const float* att_d   = (const float*)d_in[9];
    const float* b_gat   = (const float*)d_in[10];
    const float* W1      = (const float*)d_in[11];
    const float* b1      = (const float*)d_in[12];
    const float* W2      = (const float*)d_in[13];
    const float* b2      = (const float*)d_in[14];
    const float* W3      = (const float*)d_in[15];
    const float* b3      = (const float*)d_in[16];
    const int* esj = (const int*)d_in[17];
    const int* edj = (const int*)d_in[18];
    const int* esr = (const int*)d_in[19];
    const int* edr = (const int*)d_in[20];

    const int NS = in_sizes[0] / D_;
    const int NP = in_sizes[1] / D_;
    const int EJ = in_sizes[17];
    const int ER = in_sizes[19];

    float* score = (float*)d_out;
    float* alpha = score + NP;  // [ER, H] original edge order

    char* ws = (char*)d_ws;
    size_t off = 0;
    auto alloc = [&](size_t bytes) -> void* {
        void* p = ws + off;
        off = (off + bytes + 255) & ~(size_t)255;
        return p;
    };

    int* cnt_j  = (int*)alloc((size_t)4 * NP * sizeof(int));  // cnt_j|fill_j|cnt_r|fill_r
    int* fill_j = cnt_j + NP;
    int* cnt_r  = cnt_j + 2 * NP;
    int* fill_r = cnt_j + 3 * NP;
    int* off_j  = (int*)alloc((size_t)(NP + 1) * sizeof(int));
    int* off_r  = (int*)alloc((size_t)(NP + 1) * sizeof(int));
    int* sid_j  = (int*)alloc((size_t)EJ * sizeof(int));
    int* sid_r  = (int*)alloc((size_t)ER * sizeof(int));
    float* Vsrc = (float*)alloc((size_t)D_ * H_ * 4);
    float* Vdst = (float*)alloc((size_t)D_ * H_ * 4);
    float* a_src= (float*)alloc((size_t)NS * H_ * 4);
    float* a_dst= (float*)alloc((size_t)NP * H_ * 4);
    unsigned short* cat_in = (unsigned short*)alloc((size_t)NP * 2 * D_ * 2);      // [NP, 2D] bf16
    unsigned short* aggatt = (unsigned short*)alloc((size_t)NP * H_ * D_ * 2);     // [NP, H*D] bf16
    unsigned short* BT1    = (unsigned short*)alloc((size_t)D_ * 2 * D_ * 2);      // [D, 2D] bf16
    unsigned short* BTg    = (unsigned short*)alloc((size_t)D_ * H_ * D_ * 2);     // [D, H*D] bf16
    unsigned short* BTw1   = (unsigned short*)alloc((size_t)512 * 2 * D_ * 2);     // [512, 2D] bf16
    unsigned short* hcat   = (unsigned short*)alloc((size_t)NP * 2 * D_ * 2);      // [NP, 2D] bf16
    float* h1   = (float*)alloc((size_t)NP * 512 * 4);
    float* h2   = (float*)alloc((size_t)NP * 128 * 4);
    float* Pbuf = (float*)alloc((size_t)4 * NP * D_ * 4);                           // 50.3 MB split-K partials

    hipMemsetAsync(cnt_j, 0, (size_t)4 * NP * sizeof(int), stream);

    // weight repacks (fp32 [K][N] -> bf16 [N][K])
    k_tr<0><<<dim3(D_ / 64, D_ / 64), 256, 0, stream>>>(W_rel, D_, BT1, 2 * D_);
    k_tr<0><<<dim3(D_ / 64, D_ / 64), 256, 0, stream>>>(W_root, D_, BT1 + D_, 2 * D_);
    k_tr<1><<<dim3(D_ / 64, (H_ * D_) / 64), 256, 0, stream>>>(W_gs, 0, BTg, H_ * D_);
    k_tr<0><<<dim3(512 / 64, (2 * D_) / 64), 256, 0, stream>>>(W1, 512, BTw1, 2 * D_);

    k_vmat<<<2 * D_ * H_, 256, 0, stream>>>(W_gs, W_gd, att_s, att_d, Vsrc, Vdst);
    k_a<<<NS, 256, 0, stream>>>(x_skill, Vsrc, a_src, NS);
    k_a<<<NP, 256, 0, stream>>>(x_resume, Vdst, a_dst, NP);

    int egrid = (EJ + ER + 255) / 256;
    k_count<<<egrid, 256, 0, stream>>>(edj, EJ, edr, ER, cnt_j, cnt_r);
    k_scan<<<2, 64, 0, stream>>>(cnt_j, off_j, cnt_r, off_r, NP);
    k_scatter<<<egrid, 256, 0, stream>>>(edj, EJ, edr, ER, off_j, fill_j, sid_j, off_r, fill_r, sid_r);

    k_agg<<<NP, 256, 0, stream>>>(x_skill, esj, sid_j, cnt_j, off_j, cat_in);
    k_xjob<<<NP, 256, 0, stream>>>(x_job, cat_in);
    k_softmax<<<NP, 64, 0, stream>>>(a_src, a_dst, esr, sid_r, cnt_r, off_r, alpha);
    k_aggatt<<<NP, 256, 0, stream>>>(x_skill, alpha, esr, sid_r, cnt_r, off_r, aggatt);

    const int MN_f = NP * D_;        // 2048*1536
    const int MN_1 = NP * 512;

    // hcat[:, :D] = leaky([agg|x_job] @ [W_rel;W_root] + b_rel)   K=3072, S=4
    gemm_mfma_sk<<<dim3(D_ / 128, NP / 128, 4), 256, 0, stream>>>(
        cat_in, 2 * D_, BT1, 2 * D_, Pbuf, D_, 768);
    k_reduce<1><<<MN_f / 1024, 256, 0, stream>>>(Pbuf, 4, MN_f, D_, hcat, 2 * D_, b_rel, 1.f, 1);

    // hcat[:, D:] = leaky((1/H) * aggatt @ Wstack + b_gat)        K=12288, S=4
    gemm_mfma_sk<<<dim3(D_ / 128, NP / 128, 4), 256, 0, stream>>>(
        aggatt, H_ * D_, BTg, H_ * D_, Pbuf, D_, 3072);
    k_reduce<1><<<MN_f / 1024, 256, 0, stream>>>(Pbuf, 4, MN_f, D_, hcat + D_, 2 * D_, b_gat, 1.f / H_, 1);

    // h1 = leaky(hcat @ W1 + b1)  (fp32 out)                      K=3072, S=8
    gemm_mfma_sk<<<dim3(512 / 128, NP / 128, 8), 256, 0, stream>>>(
        hcat, 2 * D_, BTw1, 2 * D_, Pbuf, 512, 384);
    k_reduce<0><<<MN_1 / 1024, 256, 0, stream>>>(Pbuf, 8, MN_1, 512, h1, 512, b1, 1.f, 1);

    // h2 = leaky(h1 @ W2 + b2)  fp32
    gemm64<<<dim3(128 / 64, NP / 64), 256, 0, stream>>>(
        h1, 512, W2, 128, h2, 128, b2, 0.01f, 512);

    k_score<<<NP, 64, 0, stream>>>(h2, W3, b3, score);
}

// Round 4
// 452.863 us; speedup vs baseline: 5.4266x; 1.1403x over previous
//
#include <hip/hip_runtime.h>

#define D_ 1536
#define H_ 8

typedef __attribute__((ext_vector_type(8))) short bf16x8;
typedef __attribute__((ext_vector_type(4))) float f32x4;

__device__ __forceinline__ unsigned short f2bf(float f) {
    unsigned u = __builtin_bit_cast(unsigned, f);
    unsigned r = (u + 0x7fffu + ((u >> 16) & 1u)) >> 16;
    return (unsigned short)r;
}

__device__ __forceinline__ unsigned pack2bf(float a, float b) {
    return (unsigned)f2bf(a) | ((unsigned)f2bf(b) << 16);
}

__device__ __forceinline__ void gload16(const void* g, void* l) {
    __builtin_amdgcn_global_load_lds((const __attribute__((address_space(1))) void*)g,
                                     (__attribute__((address_space(3))) void*)l, 16, 0, 0);
}

// ---------------- V_src / V_dst: V[d,h] = sum_d2 W[d, h*D+d2] * att[h,d2] ----------------
__global__ __launch_bounds__(256) void k_vmat(const float* __restrict__ Wsrc,
                                              const float* __restrict__ Wdst,
                                              const float* __restrict__ att_s,
                                              const float* __restrict__ att_d,
                                              float* __restrict__ Vsrc,
                                              float* __restrict__ Vdst) {
    int id = blockIdx.x;
    int sel = id >= (D_ * H_);
    int idx = sel ? id - D_ * H_ : id;
    int d = idx >> 3, h = idx & 7;
    const float* W = (sel ? Wdst : Wsrc) + (size_t)d * (H_ * D_) + (size_t)h * D_;
    const float* at = (sel ? att_d : att_s) + (size_t)h * D_;
    float s = 0.f;
    for (int i = threadIdx.x; i < D_; i += 256) s += W[i] * at[i];
    for (int o = 32; o; o >>= 1) s += __shfl_down(s, o);
    __shared__ float red[4];
    if ((threadIdx.x & 63) == 0) red[threadIdx.x >> 6] = s;
    __syncthreads();
    if (threadIdx.x == 0) (sel ? Vdst : Vsrc)[d * H_ + h] = red[0] + red[1] + red[2] + red[3];
}

// ---------------- a = x @ V  ([N,D] x [D,H] -> [N,H]) ----------------
__global__ __launch_bounds__(256) void k_a(const float* __restrict__ x,
                                           const float* __restrict__ V,
                                           float* __restrict__ out, int N) {
    int n = blockIdx.x;
    if (n >= N) return;
    float part[H_] = {};
    const float* xr = x + (size_t)n * D_;
    #pragma unroll
    for (int j = 0; j < 6; j++) {
        int d = threadIdx.x + j * 256;
        float xv = xr[d];
        const float* vp = V + d * H_;
        #pragma unroll
        for (int h = 0; h < H_; h++) part[h] += xv * vp[h];
    }
    __shared__ float red[4][H_];
    int lane = threadIdx.x & 63, w = threadIdx.x >> 6;
    #pragma unroll
    for (int h = 0; h < H_; h++) {
        float v = part[h];
        for (int o = 32; o; o >>= 1) v += __shfl_down(v, o);
        if (lane == 0) red[w][h] = v;
    }
    __syncthreads();
    if (threadIdx.x < H_)
        out[(size_t)n * H_ + threadIdx.x] =
            red[0][threadIdx.x] + red[1][threadIdx.x] + red[2][threadIdx.x] + red[3][threadIdx.x];
}

// ---------------- edge counting sort ----------------
__global__ void k_count(const int* __restrict__ dj, int ej, const int* __restrict__ dr, int er,
                        int* cnt_j, int* cnt_r) {
    int i = blockIdx.x * blockDim.x + threadIdx.x;
    if (i < ej) atomicAdd(&cnt_j[dj[i]], 1);
    else if (i < ej + er) atomicAdd(&cnt_r[dr[i - ej]], 1);
}

__global__ void k_scan(const int* __restrict__ cnt_j, int* off_j,
                       const int* __restrict__ cnt_r, int* off_r, int NP) {
    const int* cnt = blockIdx.x ? cnt_r : cnt_j;
    int* off = blockIdx.x ? off_r : off_j;
    int lane = threadIdx.x;
    int chunk = (NP + 63) / 64;
    int base = lane * chunk;
    int sum = 0;
    for (int i = 0; i < chunk; i++) { int idx = base + i; if (idx < NP) sum += cnt[idx]; }
    int incl = sum;
    for (int o = 1; o < 64; o <<= 1) { int t = __shfl_up(incl, o); if (lane >= o) incl += t; }
    int run = incl - sum;
    for (int i = 0; i < chunk; i++) { int idx = base + i; if (idx < NP) { off[idx] = run; run += cnt[idx]; } }
    if (lane == 63) off[NP] = run;
}

__global__ void k_scatter(const int* __restrict__ dj, int ej, const int* __restrict__ dr, int er,
                          const int* __restrict__ off_j, int* fill_j, int* sid_j,
                          const int* __restrict__ off_r, int* fill_r, int* sid_r) {
    int i = blockIdx.x * blockDim.x + threadIdx.x;
    if (i < ej) {
        int p = dj[i];
        int slot = atomicAdd(&fill_j[p], 1);
        sid_j[off_j[p] + slot] = i;
    } else if (i < ej + er) {
        int e = i - ej;
        int p = dr[e];
        int slot = atomicAdd(&fill_r[p], 1);
        sid_r[off_r[p] + slot] = e;
    }
}

// ---------------- GraphConv aggregate -> bf16 into cat_in[:, 0:D]  (float2 + 2-edge ILP) ------
__global__ __launch_bounds__(256) void k_agg(const float* __restrict__ x, const int* __restrict__ src,
                                             const int* __restrict__ sid, const int* __restrict__ cnt,
                                             const int* __restrict__ off, unsigned* __restrict__ cat_u) {
    int p = blockIdx.x;
    int n = cnt[p], o = off[p];
    const float2* x2 = (const float2*)x;          // row stride 768 float2
    float2 acc[3] = {};
    int i = 0;
    for (; i + 2 <= n; i += 2) {
        int e0 = sid[o + i], e1 = sid[o + i + 1];
        const float2* r0 = x2 + (size_t)src[e0] * 768 + threadIdx.x;
        const float2* r1 = x2 + (size_t)src[e1] * 768 + threadIdx.x;
        float2 v0[3], v1[3];
        #pragma unroll
        for (int j = 0; j < 3; j++) { v0[j] = r0[j * 256]; v1[j] = r1[j * 256]; }
        #pragma unroll
        for (int j = 0; j < 3; j++) {
            acc[j].x += v0[j].x + v1[j].x;
            acc[j].y += v0[j].y + v1[j].y;
        }
    }
    if (i < n) {
        int e0 = sid[o + i];
        const float2* r0 = x2 + (size_t)src[e0] * 768 + threadIdx.x;
        #pragma unroll
        for (int j = 0; j < 3; j++) { float2 v = r0[j * 256]; acc[j].x += v.x; acc[j].y += v.y; }
    }
    unsigned* orow = cat_u + (size_t)p * 1536 + threadIdx.x;   // cat row = 3072 bf16 = 1536 u32
    #pragma unroll
    for (int j = 0; j < 3; j++) orow[j * 256] = pack2bf(acc[j].x, acc[j].y);
}

// ---------------- x_job -> bf16 into cat_in[:, D:2D] ----------------
__global__ __launch_bounds__(256) void k_xjob(const float* __restrict__ x_job,
                                              unsigned* __restrict__ cat_u) {
    int p = blockIdx.x;
    const float2* xr = (const float2*)x_job + (size_t)p * 768 + threadIdx.x;
    unsigned* orow = cat_u + (size_t)p * 1536 + 768 + threadIdx.x;
    #pragma unroll
    for (int j = 0; j < 3; j++) { float2 v = xr[j * 256]; orow[j * 256] = pack2bf(v.x, v.y); }
}

// ---------------- GAT segment softmax -> alpha (original edge order, fp32) ----------------
__global__ void k_softmax(const float* __restrict__ a_src, const float* __restrict__ a_dst,
                          const int* __restrict__ src, const int* __restrict__ sid,
                          const int* __restrict__ cnt, const int* __restrict__ off,
                          float* __restrict__ alpha_out) {
    int p = blockIdx.x;
    int n = cnt[p], o = off[p];
    if (n == 0) return;
    int lane = threadIdx.x;
    #pragma unroll 1
    for (int h = 0; h < H_; h++) {
        float ad = a_dst[(size_t)p * H_ + h];
        float m = -3.4e38f;
        for (int i = lane; i < n; i += 64) {
            int e = sid[o + i];
            float v = a_src[(size_t)src[e] * H_ + h] + ad;
            v = v >= 0.f ? v : 0.2f * v;
            m = fmaxf(m, v);
        }
        for (int o2 = 32; o2; o2 >>= 1) m = fmaxf(m, __shfl_xor(m, o2));
        float s = 0.f;
        for (int i = lane; i < n; i += 64) {
            int e = sid[o + i];
            float v = a_src[(size_t)src[e] * H_ + h] + ad;
            v = v >= 0.f ? v : 0.2f * v;
            s += expf(v - m);
        }
        for (int o2 = 32; o2; o2 >>= 1) s += __shfl_xor(s, o2);
        float inv = 1.f / (s + 1e-16f);
        for (int i = lane; i < n; i += 64) {
            int e = sid[o + i];
            float v = a_src[(size_t)src[e] * H_ + h] + ad;
            v = v >= 0.f ? v : 0.2f * v;
            alpha_out[(size_t)e * H_ + h] = expf(v - m) * inv;
        }
    }
}

// ---------------- attention-weighted aggregate (input space) -> bf16 (float2 + 2-edge ILP) ----
__global__ __launch_bounds__(256) void k_aggatt(const float* __restrict__ x,
                                                const float* __restrict__ alpha,
                                                const int* __restrict__ src, const int* __restrict__ sid,
                                                const int* __restrict__ cnt, const int* __restrict__ off,
                                                unsigned* __restrict__ aggatt_u) {
    int p = blockIdx.x;
    int n = cnt[p], o = off[p];
    const float2* x2 = (const float2*)x;
    float2 acc[H_][3] = {};
    int i = 0;
    for (; i + 2 <= n; i += 2) {
        int e0 = sid[o + i], e1 = sid[o + i + 1];
        const float2* r0 = x2 + (size_t)src[e0] * 768 + threadIdx.x;
        const float2* r1 = x2 + (size_t)src[e1] * 768 + threadIdx.x;
        float2 v0[3], v1[3];
        #pragma unroll
        for (int j = 0; j < 3; j++) { v0[j] = r0[j * 256]; v1[j] = r1[j * 256]; }
        const float* a0 = alpha + (size_t)e0 * H_;
        const float* a1 = alpha + (size_t)e1 * H_;
        #pragma unroll
        for (int h = 0; h < H_; h++) {
            float w0 = a0[h], w1 = a1[h];
            #pragma unroll
            for (int j = 0; j < 3; j++) {
                acc[h][j].x += w0 * v0[j].x + w1 * v1[j].x;
                acc[h][j].y += w0 * v0[j].y + w1 * v1[j].y;
            }
        }
    }
    if (i < n) {
        int e0 = sid[o + i];
        const float2* r0 = x2 + (size_t)src[e0] * 768 + threadIdx.x;
        float2 v0[3];
        #pragma unroll
        for (int j = 0; j < 3; j++) v0[j] = r0[j * 256];
        const float* a0 = alpha + (size_t)e0 * H_;
        #pragma unroll
        for (int h = 0; h < H_; h++) {
            float w0 = a0[h];
            #pragma unroll
            for (int j = 0; j < 3; j++) { acc[h][j].x += w0 * v0[j].x; acc[h][j].y += w0 * v0[j].y; }
        }
    }
    unsigned* orow = aggatt_u + (size_t)p * (H_ * 768) + threadIdx.x;   // head block = 768 u32
    #pragma unroll
    for (int h = 0; h < H_; h++)
        #pragma unroll
        for (int j = 0; j < 3; j++)
            orow[h * 768 + j * 256] = pack2bf(acc[h][j].x, acc[h][j].y);
}

// ---------------- fp32 [K][N] -> bf16 [N][K] transpose (GATB: permuted stacked weights) ----------
template <int GATB>
__global__ __launch_bounds__(256) void k_tr(const float* __restrict__ in, int ldin,
                                            unsigned short* __restrict__ out, int ldout) {
    __shared__ float t[64][65];
    int k0 = blockIdx.y * 64, n0 = blockIdx.x * 64;
    int tx = threadIdx.x & 63, ty = threadIdx.x >> 6;
    #pragma unroll
    for (int i = 0; i < 16; i++) {
        int k = k0 + ty + i * 4;
        const float* rp;
        if (GATB) {
            int d2 = k % D_, h = k / D_;
            rp = in + (size_t)d2 * (H_ * D_) + (size_t)h * D_;
        } else {
            rp = in + (size_t)k * ldin;
        }
        t[ty + i * 4][tx] = rp[n0 + tx];
    }
    __syncthreads();
    #pragma unroll
    for (int i = 0; i < 16; i++) {
        int n = n0 + ty + i * 4;
        out[(size_t)n * ldout + k0 + tx] = f2bf(t[tx][ty + i * 4]);
    }
}

// ---------------- bf16 MFMA GEMM, split-K, 2-phase double-buffered pipeline ----------------
// grid: x = N/128, y = M/128, z = splits. Partial P[z][m][n] fp32.
// LDS: double buffer; row r (64B = 4 slots of 16B), stored slot sl holds global slot sl^((r>>1)&3).
// Pipeline: stage(next) -> vmcnt(4) -> barrier -> ds_read(cur) -> setprio1 MFMA setprio0 -> barrier.
__global__ __launch_bounds__(256) void gemm_sk2(const unsigned short* __restrict__ A, int lda,
                                                const unsigned short* __restrict__ BT, int ldb,
                                                float* __restrict__ P, int N, int Kc) {
    __shared__ unsigned short As[2][128 * 32];
    __shared__ unsigned short Bs[2][128 * 32];
    int tid = threadIdx.x;
    int lane = tid & 63, wid = tid >> 6;

    int nwg = gridDim.x * gridDim.y;
    int bidh = blockIdx.y * gridDim.x + blockIdx.x;
    int swz = (bidh & 7) * (nwg >> 3) + (bidh >> 3);
    int bn = (swz % gridDim.x) * 128;
    int bm = (swz / gridDim.x) * 128;

    int kbase = blockIdx.z * Kc, kend = kbase + Kc;
    int wr = wid >> 1, wc = wid & 1;
    int fr = lane & 15, g = lane >> 4;
    int srow = lane >> 2, ssl = lane & 3;

    f32x4 acc[4][4] = {};

    auto stage = [&](int buf, int k0) {
        #pragma unroll
        for (int i = 0; i < 2; i++) {
            int c = wid * 2 + i;
            int r = c * 16 + srow;
            int sg = ssl ^ ((r >> 1) & 3);
            gload16(A + (size_t)(bm + r) * lda + k0 + sg * 8, &As[buf][c * 512]);
            gload16(BT + (size_t)(bn + r) * ldb + k0 + sg * 8, &Bs[buf][c * 512]);
        }
    };

    stage(0, kbase);
    int cur = 0;
    for (int k0 = kbase; k0 < kend; k0 += 32) {
        if (k0 + 32 < kend) {
            stage(cur ^ 1, k0 + 32);                     // prefetch next tile (4 loads/wave)
            asm volatile("s_waitcnt vmcnt(4)" ::: "memory");  // wait only the PREVIOUS stage
        } else {
            asm volatile("s_waitcnt vmcnt(0)" ::: "memory");
        }
        __builtin_amdgcn_s_barrier();                    // buf[cur] published
        __builtin_amdgcn_sched_barrier(0);               // pin: no ds_read hoist above barrier
        bf16x8 a[4], b[4];
        #pragma unroll
        for (int mi = 0; mi < 4; mi++) {
            int row = wr * 64 + mi * 16 + fr;
            a[mi] = *(const bf16x8*)(&As[cur][row * 32 + ((g ^ ((row >> 1) & 3)) * 8)]);
        }
        #pragma unroll
        for (int ni = 0; ni < 4; ni++) {
            int row = wc * 64 + ni * 16 + fr;
            b[ni] = *(const bf16x8*)(&Bs[cur][row * 32 + ((g ^ ((row >> 1) & 3)) * 8)]);
        }
        __builtin_amdgcn_s_setprio(1);
        #pragma unroll
        for (int mi = 0; mi < 4; mi++)
            #pragma unroll
            for (int ni = 0; ni < 4; ni++)
                acc[mi][ni] = __builtin_amdgcn_mfma_f32_16x16x32_bf16(a[mi], b[ni], acc[mi][ni], 0, 0, 0);
        __builtin_amdgcn_s_setprio(0);
        __builtin_amdgcn_s_barrier();                    // all waves done reading buf[cur]
        __builtin_amdgcn_sched_barrier(0);               // pin: next stage can't hoist above
        cur ^= 1;
    }

    size_t MN = (size_t)N * (size_t)(gridDim.y * 128);
    float* Pz = P + (size_t)blockIdx.z * MN;
    #pragma unroll
    for (int mi = 0; mi < 4; mi++) {
        int r0 = bm + wr * 64 + mi * 16 + (lane >> 4) * 4;
        #pragma unroll
        for (int ni = 0; ni < 4; ni++) {
            int c = bn + wc * 64 + ni * 16 + (lane & 15);
            #pragma unroll
            for (int j = 0; j < 4; j++)
                Pz[(size_t)(r0 + j) * N + c] = acc[mi][ni][j];
        }
    }
}

// ---------------- split-K reduce + epilogue ----------------
template <int OUT_BF16>
__global__ __launch_bounds__(256) void k_reduce(const float* __restrict__ P, int S, int MN, int N,
                                                void* __restrict__ Cout, int ldc,
                                                const float* __restrict__ bias, float scale,
                                                int useLeaky) {
    int idx = (blockIdx.x * 256 + threadIdx.x) * 4;
    if (idx >= MN) return;
    float4 v = *(const float4*)(P + idx);
    for (int s = 1; s < S; s++) {
        float4 t = *(const float4*)(P + (size_t)s * MN + idx);
        v.x += t.x; v.y += t.y; v.z += t.z; v.w += t.w;
    }
    int m = idx / N, n = idx - m * N;
    float vv[4] = {v.x, v.y, v.z, v.w};
    #pragma unroll
    for (int j = 0; j < 4; j++) {
        float x = vv[j] * scale + bias[n + j];
        if (useLeaky) x = x >= 0.f ? x : 0.01f * x;
        if (OUT_BF16) ((unsigned short*)Cout)[(size_t)m * ldc + n + j] = f2bf(x);
        else ((float*)Cout)[(size_t)m * ldc + n + j] = x;
    }
}

// ---------------- final score: dot(h2[p], W3) + b3 ----------------
__global__ void k_score(const float* __restrict__ h2, const float* __restrict__ W3,
                        const float* __restrict__ b3, float* __restrict__ out) {
    int p = blockIdx.x;
    int lane = threadIdx.x;
    const float* r = h2 + (size_t)p * 128;
    float s = r[lane] * W3[lane] + r[lane + 64] * W3[lane + 64];
    for (int o = 32; o; o >>= 1) s += __shfl_down(s, o);
    if (lane == 0) out[p] = s + b3[0];
}

extern "C" void kernel_launch(void* const* d_in, const int* in_sizes, int n_in,
                              void* d_out, int out_size, void* d_ws, size_t ws_size,
                              hipStream_t stream) {
    const float* x_skill = (const float*)d_in[0];
    const float* x_job   = (const float*)d_in[1];
    const float* x_resume= (const float*)d_in[2];
    const float* W_rel   = (const float*)d_in[3];
    const float* b_rel   = (const float*)d_in[4];
    const float* W_root  = (const float*)d_in[5];
    const float* W_gs    = (const float*)d_in[6];
    const float* W_gd    = (const float*)d_in[7];
    const float* att_s   = (const float*)d_in[8];
    const float* att_d   = (const float*)d_in[9];
    const float* b_gat   = (const float*)d_in[10];
    const float* W1      = (const float*)d_in[11];
    const float* b1      = (const float*)d_in[12];
    const float* W2      = (const float*)d_in[13];
    const float* b2      = (const float*)d_in[14];
    const float* W3      = (const float*)d_in[15];
    const float* b3      = (const float*)d_in[16];
    const int* esj = (const int*)d_in[17];
    const int* edj = (const int*)d_in[18];
    const int* esr = (const int*)d_in[19];
    const int* edr = (const int*)d_in[20];

    const int NS = in_sizes[0] / D_;
    const int NP = in_sizes[1] / D_;
    const int EJ = in_sizes[17];
    const int ER = in_sizes[19];

    float* score = (float*)d_out;
    float* alpha = score + NP;  // [ER, H] original edge order

    char* ws = (char*)d_ws;
    size_t off = 0;
    auto alloc = [&](size_t bytes) -> void* {
        void* p = ws + off;
        off = (off + bytes + 255) & ~(size_t)255;
        return p;
    };

    int* cnt_j  = (int*)alloc((size_t)4 * NP * sizeof(int));  // cnt_j|fill_j|cnt_r|fill_r
    int* fill_j = cnt_j + NP;
    int* cnt_r  = cnt_j + 2 * NP;
    int* fill_r = cnt_j + 3 * NP;
    int* off_j  = (int*)alloc((size_t)(NP + 1) * sizeof(int));
    int* off_r  = (int*)alloc((size_t)(NP + 1) * sizeof(int));
    int* sid_j  = (int*)alloc((size_t)EJ * sizeof(int));
    int* sid_r  = (int*)alloc((size_t)ER * sizeof(int));
    float* Vsrc = (float*)alloc((size_t)D_ * H_ * 4);
    float* Vdst = (float*)alloc((size_t)D_ * H_ * 4);
    float* a_src= (float*)alloc((size_t)NS * H_ * 4);
    float* a_dst= (float*)alloc((size_t)NP * H_ * 4);
    unsigned short* cat_in = (unsigned short*)alloc((size_t)NP * 2 * D_ * 2);      // [NP, 2D] bf16
    unsigned short* aggatt = (unsigned short*)alloc((size_t)NP * H_ * D_ * 2);     // [NP, H*D] bf16
    unsigned short* BT1    = (unsigned short*)alloc((size_t)D_ * 2 * D_ * 2);      // [D, 2D] bf16
    unsigned short* BTg    = (unsigned short*)alloc((size_t)D_ * H_ * D_ * 2);     // [D, H*D] bf16
    unsigned short* BTw1   = (unsigned short*)alloc((size_t)512 * 2 * D_ * 2);     // [512, 2D] bf16
    unsigned short* BTw2   = (unsigned short*)alloc((size_t)128 * 512 * 2);        // [128, 512] bf16
    unsigned short* hcat   = (unsigned short*)alloc((size_t)NP * 2 * D_ * 2);      // [NP, 2D] bf16
    unsigned short* h1b    = (unsigned short*)alloc((size_t)NP * 512 * 2);         // [NP, 512] bf16
    float* h2   = (float*)alloc((size_t)NP * 128 * 4);
    float* Pbuf = (float*)alloc((size_t)4 * NP * D_ * 4);                           // 50.3 MB split-K partials

    hipMemsetAsync(cnt_j, 0, (size_t)4 * NP * sizeof(int), stream);

    // weight repacks (fp32 [K][N] -> bf16 [N][K])
    k_tr<0><<<dim3(D_ / 64, D_ / 64), 256, 0, stream>>>(W_rel, D_, BT1, 2 * D_);
    k_tr<0><<<dim3(D_ / 64, D_ / 64), 256, 0, stream>>>(W_root, D_, BT1 + D_, 2 * D_);
    k_tr<1><<<dim3(D_ / 64, (H_ * D_) / 64), 256, 0, stream>>>(W_gs, 0, BTg, H_ * D_);
    k_tr<0><<<dim3(512 / 64, (2 * D_) / 64), 256, 0, stream>>>(W1, 512, BTw1, 2 * D_);
    k_tr<0><<<dim3(128 / 64, 512 / 64), 256, 0, stream>>>(W2, 128, BTw2, 512);

    k_vmat<<<2 * D_ * H_, 256, 0, stream>>>(W_gs, W_gd, att_s, att_d, Vsrc, Vdst);
    k_a<<<NS, 256, 0, stream>>>(x_skill, Vsrc, a_src, NS);
    k_a<<<NP, 256, 0, stream>>>(x_resume, Vdst, a_dst, NP);

    int egrid = (EJ + ER + 255) / 256;
    k_count<<<egrid, 256, 0, stream>>>(edj, EJ, edr, ER, cnt_j, cnt_r);
    k_scan<<<2, 64, 0, stream>>>(cnt_j, off_j, cnt_r, off_r, NP);
    k_scatter<<<egrid, 256, 0, stream>>>(edj, EJ, edr, ER, off_j, fill_j, sid_j, off_r, fill_r, sid_r);

    k_agg<<<NP, 256, 0, stream>>>(x_skill, esj, sid_j, cnt_j, off_j, (unsigned*)cat_in);
    k_xjob<<<NP, 256, 0, stream>>>(x_job, (unsigned*)cat_in);
    k_softmax<<<NP, 64, 0, stream>>>(a_src, a_dst, esr, sid_r, cnt_r, off_r, alpha);
    k_aggatt<<<NP, 256, 0, stream>>>(x_skill, alpha, esr, sid_r, cnt_r, off_r, (unsigned*)aggatt);

    const int MN_f = NP * D_;        // 2048*1536
    const int MN_1 = NP * 512;
    const int MN_2 = NP * 128;

    // hcat[:, :D] = leaky([agg|x_job] @ [W_rel;W_root] + b_rel)   K=3072, S=4
    gemm_sk2<<<dim3(D_ / 128, NP / 128, 4), 256, 0, stream>>>(
        cat_in, 2 * D_, BT1, 2 * D_, Pbuf, D_, 768);
    k_reduce<1><<<MN_f / 1024, 256, 0, stream>>>(Pbuf, 4, MN_f, D_, hcat, 2 * D_, b_rel, 1.f, 1);

    // hcat[:, D:] = leaky((1/H) * aggatt @ Wstack + b_gat)        K=12288, S=4
    gemm_sk2<<<dim3(D_ / 128, NP / 128, 4), 256, 0, stream>>>(
        aggatt, H_ * D_, BTg, H_ * D_, Pbuf, D_, 3072);
    k_reduce<1><<<MN_f / 1024, 256, 0, stream>>>(Pbuf, 4, MN_f, D_, hcat + D_, 2 * D_, b_gat, 1.f / H_, 1);

    // h1 = leaky(hcat @ W1 + b1) -> bf16                          K=3072, S=8
    gemm_sk2<<<dim3(512 / 128, NP / 128, 8), 256, 0, stream>>>(
        hcat, 2 * D_, BTw1, 2 * D_, Pbuf, 512, 384);
    k_reduce<1><<<MN_1 / 1024, 256, 0, stream>>>(Pbuf, 8, MN_1, 512, h1b, 512, b1, 1.f, 1);

    // h2 = leaky(h1 @ W2 + b2) -> fp32                            K=512, S=4
    gemm_sk2<<<dim3(128 / 128, NP / 128, 4), 256, 0, stream>>>(
        h1b, 512, BTw2, 512, Pbuf, 128, 128);
    k_reduce<0><<<MN_2 / 1024, 256, 0, stream>>>(Pbuf, 4, MN_2, 128, h2, 128, b2, 1.f, 1);

    k_score<<<NP, 64, 0, stream>>>(h2, W3, b3, score);
}

// Round 5
// 452.111 us; speedup vs baseline: 5.4356x; 1.0017x over previous
//
#include <hip/hip_runtime.h>

#define D_ 1536
#define H_ 8

typedef __attribute__((ext_vector_type(8))) short bf16x8;
typedef __attribute__((ext_vector_type(4))) float f32x4;

__device__ __forceinline__ unsigned short f2bf(float f) {
    unsigned u = __builtin_bit_cast(unsigned, f);
    unsigned r = (u + 0x7fffu + ((u >> 16) & 1u)) >> 16;
    return (unsigned short)r;
}

__device__ __forceinline__ unsigned pack2bf(float a, float b) {
    return (unsigned)f2bf(a) | ((unsigned)f2bf(b) << 16);
}

__device__ __forceinline__ float bflo(unsigned u) { return __builtin_bit_cast(float, u << 16); }
__device__ __forceinline__ float bfhi(unsigned u) { return __builtin_bit_cast(float, u & 0xffff0000u); }

__device__ __forceinline__ void gload16(const void* g, void* l) {
    __builtin_amdgcn_global_load_lds((const __attribute__((address_space(1))) void*)g,
                                     (__attribute__((address_space(3))) void*)l, 16, 0, 0);
}

// ---------------- V_src / V_dst ----------------
__global__ __launch_bounds__(256) void k_vmat(const float* __restrict__ Wsrc,
                                              const float* __restrict__ Wdst,
                                              const float* __restrict__ att_s,
                                              const float* __restrict__ att_d,
                                              float* __restrict__ Vsrc,
                                              float* __restrict__ Vdst) {
    int id = blockIdx.x;
    int sel = id >= (D_ * H_);
    int idx = sel ? id - D_ * H_ : id;
    int d = idx >> 3, h = idx & 7;
    const float* W = (sel ? Wdst : Wsrc) + (size_t)d * (H_ * D_) + (size_t)h * D_;
    const float* at = (sel ? att_d : att_s) + (size_t)h * D_;
    float s = 0.f;
    for (int i = threadIdx.x; i < D_; i += 256) s += W[i] * at[i];
    for (int o = 32; o; o >>= 1) s += __shfl_down(s, o);
    __shared__ float red[4];
    if ((threadIdx.x & 63) == 0) red[threadIdx.x >> 6] = s;
    __syncthreads();
    if (threadIdx.x == 0) (sel ? Vdst : Vsrc)[d * H_ + h] = red[0] + red[1] + red[2] + red[3];
}

// ---------------- a = x @ V ----------------
__global__ __launch_bounds__(256) void k_a(const float* __restrict__ x,
                                           const float* __restrict__ V,
                                           float* __restrict__ out, int N) {
    int n = blockIdx.x;
    if (n >= N) return;
    float part[H_] = {};
    const float* xr = x + (size_t)n * D_;
    #pragma unroll
    for (int j = 0; j < 6; j++) {
        int d = threadIdx.x + j * 256;
        float xv = xr[d];
        const float* vp = V + d * H_;
        #pragma unroll
        for (int h = 0; h < H_; h++) part[h] += xv * vp[h];
    }
    __shared__ float red[4][H_];
    int lane = threadIdx.x & 63, w = threadIdx.x >> 6;
    #pragma unroll
    for (int h = 0; h < H_; h++) {
        float v = part[h];
        for (int o = 32; o; o >>= 1) v += __shfl_down(v, o);
        if (lane == 0) red[w][h] = v;
    }
    __syncthreads();
    if (threadIdx.x < H_)
        out[(size_t)n * H_ + threadIdx.x] =
            red[0][threadIdx.x] + red[1][threadIdx.x] + red[2][threadIdx.x] + red[3][threadIdx.x];
}

// ---------------- edge counting sort ----------------
__global__ void k_count(const int* __restrict__ dj, int ej, const int* __restrict__ dr, int er,
                        int* cnt_j, int* cnt_r) {
    int i = blockIdx.x * blockDim.x + threadIdx.x;
    if (i < ej) atomicAdd(&cnt_j[dj[i]], 1);
    else if (i < ej + er) atomicAdd(&cnt_r[dr[i - ej]], 1);
}

__global__ void k_scan(const int* __restrict__ cnt_j, int* off_j,
                       const int* __restrict__ cnt_r, int* off_r, int NP) {
    const int* cnt = blockIdx.x ? cnt_r : cnt_j;
    int* off = blockIdx.x ? off_r : off_j;
    int lane = threadIdx.x;
    int chunk = (NP + 63) / 64;
    int base = lane * chunk;
    int sum = 0;
    for (int i = 0; i < chunk; i++) { int idx = base + i; if (idx < NP) sum += cnt[idx]; }
    int incl = sum;
    for (int o = 1; o < 64; o <<= 1) { int t = __shfl_up(incl, o); if (lane >= o) incl += t; }
    int run = incl - sum;
    for (int i = 0; i < chunk; i++) { int idx = base + i; if (idx < NP) { off[idx] = run; run += cnt[idx]; } }
    if (lane == 63) off[NP] = run;
}

__global__ void k_scatter(const int* __restrict__ dj, int ej, const int* __restrict__ dr, int er,
                          const int* __restrict__ off_j, int* fill_j, int* sid_j,
                          const int* __restrict__ off_r, int* fill_r, int* sid_r) {
    int i = blockIdx.x * blockDim.x + threadIdx.x;
    if (i < ej) {
        int p = dj[i];
        int slot = atomicAdd(&fill_j[p], 1);
        sid_j[off_j[p] + slot] = i;
    } else if (i < ej + er) {
        int e = i - ej;
        int p = dr[e];
        int slot = atomicAdd(&fill_r[p], 1);
        sid_r[off_r[p] + slot] = e;
    }
}

// ---------------- x_skill fp32 -> bf16 (u32-packed) ----------------
__global__ __launch_bounds__(256) void k_xsb(const float* __restrict__ x, unsigned* __restrict__ xb) {
    int p = blockIdx.x;
    const float2* xr = (const float2*)x + (size_t)p * 768 + threadIdx.x;
    unsigned* o = xb + (size_t)p * 768 + threadIdx.x;
    #pragma unroll
    for (int j = 0; j < 3; j++) { float2 v = xr[j * 256]; o[j * 256] = pack2bf(v.x, v.y); }
}

// ---------------- GraphConv aggregate (bf16 gather) -> cat_in[:, 0:D] ----------------
__global__ __launch_bounds__(256) void k_agg(const unsigned* __restrict__ xb, const int* __restrict__ src,
                                             const int* __restrict__ sid, const int* __restrict__ cnt,
                                             const int* __restrict__ off, unsigned* __restrict__ cat_u) {
    int p = blockIdx.x;
    int n = cnt[p], o = off[p];
    float2 acc[3] = {};
    int i = 0;
    for (; i + 2 <= n; i += 2) {
        int e0 = sid[o + i], e1 = sid[o + i + 1];
        const unsigned* r0 = xb + (size_t)src[e0] * 768 + threadIdx.x;
        const unsigned* r1 = xb + (size_t)src[e1] * 768 + threadIdx.x;
        unsigned v0[3], v1[3];
        #pragma unroll
        for (int j = 0; j < 3; j++) { v0[j] = r0[j * 256]; v1[j] = r1[j * 256]; }
        #pragma unroll
        for (int j = 0; j < 3; j++) {
            acc[j].x += bflo(v0[j]) + bflo(v1[j]);
            acc[j].y += bfhi(v0[j]) + bfhi(v1[j]);
        }
    }
    if (i < n) {
        int e0 = sid[o + i];
        const unsigned* r0 = xb + (size_t)src[e0] * 768 + threadIdx.x;
        #pragma unroll
        for (int j = 0; j < 3; j++) { unsigned v = r0[j * 256]; acc[j].x += bflo(v); acc[j].y += bfhi(v); }
    }
    unsigned* orow = cat_u + (size_t)p * 1536 + threadIdx.x;
    #pragma unroll
    for (int j = 0; j < 3; j++) orow[j * 256] = pack2bf(acc[j].x, acc[j].y);
}

// ---------------- x_job -> bf16 into cat_in[:, D:2D] ----------------
__global__ __launch_bounds__(256) void k_xjob(const float* __restrict__ x_job,
                                              unsigned* __restrict__ cat_u) {
    int p = blockIdx.x;
    const float2* xr = (const float2*)x_job + (size_t)p * 768 + threadIdx.x;
    unsigned* orow = cat_u + (size_t)p * 1536 + 768 + threadIdx.x;
    #pragma unroll
    for (int j = 0; j < 3; j++) { float2 v = xr[j * 256]; orow[j * 256] = pack2bf(v.x, v.y); }
}

// ---------------- GAT segment softmax -> alpha (fp32, original edge order) ----------------
__global__ void k_softmax(const float* __restrict__ a_src, const float* __restrict__ a_dst,
                          const int* __restrict__ src, const int* __restrict__ sid,
                          const int* __restrict__ cnt, const int* __restrict__ off,
                          float* __restrict__ alpha_out) {
    int p = blockIdx.x;
    int n = cnt[p], o = off[p];
    if (n == 0) return;
    int lane = threadIdx.x;
    #pragma unroll 1
    for (int h = 0; h < H_; h++) {
        float ad = a_dst[(size_t)p * H_ + h];
        float m = -3.4e38f;
        for (int i = lane; i < n; i += 64) {
            int e = sid[o + i];
            float v = a_src[(size_t)src[e] * H_ + h] + ad;
            v = v >= 0.f ? v : 0.2f * v;
            m = fmaxf(m, v);
        }
        for (int o2 = 32; o2; o2 >>= 1) m = fmaxf(m, __shfl_xor(m, o2));
        float s = 0.f;
        for (int i = lane; i < n; i += 64) {
            int e = sid[o + i];
            float v = a_src[(size_t)src[e] * H_ + h] + ad;
            v = v >= 0.f ? v : 0.2f * v;
            s += expf(v - m);
        }
        for (int o2 = 32; o2; o2 >>= 1) s += __shfl_xor(s, o2);
        float inv = 1.f / (s + 1e-16f);
        for (int i = lane; i < n; i += 64) {
            int e = sid[o + i];
            float v = a_src[(size_t)src[e] * H_ + h] + ad;
            v = v >= 0.f ? v : 0.2f * v;
            alpha_out[(size_t)e * H_ + h] = expf(v - m) * inv;
        }
    }
}

// ---------------- attention-weighted aggregate (bf16 gather) -> aggatt bf16 ----------------
__global__ __launch_bounds__(256) void k_aggatt(const unsigned* __restrict__ xb,
                                                const float* __restrict__ alpha,
                                                const int* __restrict__ src, const int* __restrict__ sid,
                                                const int* __restrict__ cnt, const int* __restrict__ off,
                                                unsigned* __restrict__ aggatt_u) {
    int p = blockIdx.x;
    int n = cnt[p], o = off[p];
    float2 acc[H_][3] = {};
    int i = 0;
    for (; i + 2 <= n; i += 2) {
        int e0 = sid[o + i], e1 = sid[o + i + 1];
        const unsigned* r0 = xb + (size_t)src[e0] * 768 + threadIdx.x;
        const unsigned* r1 = xb + (size_t)src[e1] * 768 + threadIdx.x;
        unsigned v0[3], v1[3];
        #pragma unroll
        for (int j = 0; j < 3; j++) { v0[j] = r0[j * 256]; v1[j] = r1[j * 256]; }
        const float* a0 = alpha + (size_t)e0 * H_;
        const float* a1 = alpha + (size_t)e1 * H_;
        float f0[3][2], f1[3][2];
        #pragma unroll
        for (int j = 0; j < 3; j++) {
            f0[j][0] = bflo(v0[j]); f0[j][1] = bfhi(v0[j]);
            f1[j][0] = bflo(v1[j]); f1[j][1] = bfhi(v1[j]);
        }
        #pragma unroll
        for (int h = 0; h < H_; h++) {
            float w0 = a0[h], w1 = a1[h];
            #pragma unroll
            for (int j = 0; j < 3; j++) {
                acc[h][j].x += w0 * f0[j][0] + w1 * f1[j][0];
                acc[h][j].y += w0 * f0[j][1] + w1 * f1[j][1];
            }
        }
    }
    if (i < n) {
        int e0 = sid[o + i];
        const unsigned* r0 = xb + (size_t)src[e0] * 768 + threadIdx.x;
        unsigned v0[3];
        #pragma unroll
        for (int j = 0; j < 3; j++) v0[j] = r0[j * 256];
        const float* a0 = alpha + (size_t)e0 * H_;
        #pragma unroll
        for (int h = 0; h < H_; h++) {
            float w0 = a0[h];
            #pragma unroll
            for (int j = 0; j < 3; j++) {
                acc[h][j].x += w0 * bflo(v0[j]);
                acc[h][j].y += w0 * bfhi(v0[j]);
            }
        }
    }
    unsigned* orow = aggatt_u + (size_t)p * (H_ * 768) + threadIdx.x;
    #pragma unroll
    for (int h = 0; h < H_; h++)
        #pragma unroll
        for (int j = 0; j < 3; j++)
            orow[h * 768 + j * 256] = pack2bf(acc[h][j].x, acc[h][j].y);
}

// ---------------- fp32 [K][N] -> bf16 [N][K] transpose (u32-packed stores) ----------------
template <int GATB>
__global__ __launch_bounds__(256) void k_tr(const float* __restrict__ in, int ldin,
                                            unsigned short* __restrict__ out, int ldout) {
    __shared__ float t[64][65];
    int k0 = blockIdx.y * 64, n0 = blockIdx.x * 64;
    int tx = threadIdx.x & 63, ty = threadIdx.x >> 6;
    #pragma unroll
    for (int i = 0; i < 16; i++) {
        int k = k0 + ty + i * 4;
        const float* rp;
        if (GATB) {
            int d2 = k % D_, h = k / D_;
            rp = in + (size_t)d2 * (H_ * D_) + (size_t)h * D_;
        } else {
            rp = in + (size_t)k * ldin;
        }
        t[ty + i * 4][tx] = rp[n0 + tx];
    }
    __syncthreads();
    int tx2 = threadIdx.x & 31, ty2 = threadIdx.x >> 5;   // k-pair, row group
    #pragma unroll
    for (int i = 0; i < 8; i++) {
        int nl = ty2 + i * 8;
        unsigned v = pack2bf(t[tx2 * 2][nl], t[tx2 * 2 + 1][nl]);
        *(unsigned*)(out + (size_t)(n0 + nl) * ldout + k0 + tx2 * 2) = v;
    }
}

// ---------------- bf16 MFMA GEMM: BM=256 BN=128, 8 waves, split-K, 2-phase dbuf pipeline ------
// grid: x = N/128, y = M/256, z = S. Uneven K split: steps = bs + (z < extra).
__global__ __launch_bounds__(512, 4) void gemm_sk(const unsigned short* __restrict__ A, int lda,
                                                  const unsigned short* __restrict__ BT, int ldb,
                                                  float* __restrict__ P, int N, int bs, int extra) {
    __shared__ unsigned short As[2][256 * 32];
    __shared__ unsigned short Bs[2][128 * 32];
    int tid = threadIdx.x;
    int lane = tid & 63, wid = tid >> 6;

    int nwg = gridDim.x * gridDim.y;
    int bidh = blockIdx.y * gridDim.x + blockIdx.x;
    int swz = (bidh & 7) * (nwg >> 3) + (bidh >> 3);
    int bn = (swz % gridDim.x) * 128;
    int bm = (swz / gridDim.x) * 256;

    int z = blockIdx.z;
    int steps = bs + (z < extra);
    int kb = z * bs + min(z, extra);
    int kbase = kb * 32, kend = kbase + steps * 32;

    int wr = wid >> 1, wc = wid & 1;            // 4 x 2 wave grid, wave tile 64x64
    int fr = lane & 15, g = lane >> 4;

    // staging: A has 1024 16B-chunks (row = c>>2, slot = c&3), B has 512.
    int ra0 = tid >> 2, sa0 = tid & 3;          // A chunk tid
    int ra1 = (tid + 512) >> 2, sa1 = tid & 3;  // A chunk tid+512
    int sg_a0 = sa0 ^ ((ra0 >> 1) & 3);
    int sg_a1 = sa1 ^ ((ra1 >> 1) & 3);
    int sg_b = sa0 ^ ((ra0 >> 1) & 3);          // B chunk tid: same row/slot decomposition

    f32x4 acc[4][4] = {};

    auto stage = [&](int buf, int k0) {
        gload16(A + (size_t)(bm + ra0) * lda + k0 + sg_a0 * 8, &As[buf][tid * 8]);
        gload16(A + (size_t)(bm + ra1) * lda + k0 + sg_a1 * 8, &As[buf][(tid + 512) * 8]);
        gload16(BT + (size_t)(bn + ra0) * ldb + k0 + sg_b * 8, &Bs[buf][tid * 8]);
    };

    stage(0, kbase);
    int cur = 0;
    for (int k0 = kbase; k0 < kend; k0 += 32) {
        if (k0 + 32 < kend) {
            stage(cur ^ 1, k0 + 32);
            asm volatile("s_waitcnt vmcnt(3)" ::: "memory");   // previous stage (3 loads) landed
        } else {
            asm volatile("s_waitcnt vmcnt(0)" ::: "memory");
        }
        __builtin_amdgcn_s_barrier();
        __builtin_amdgcn_sched_barrier(0);
        bf16x8 a[4], b[4];
        #pragma unroll
        for (int mi = 0; mi < 4; mi++) {
            int row = wr * 64 + mi * 16 + fr;
            a[mi] = *(const bf16x8*)(&As[cur][row * 32 + ((g ^ ((row >> 1) & 3)) * 8)]);
        }
        #pragma unroll
        for (int ni = 0; ni < 4; ni++) {
            int row = wc * 64 + ni * 16 + fr;
            b[ni] = *(const bf16x8*)(&Bs[cur][row * 32 + ((g ^ ((row >> 1) & 3)) * 8)]);
        }
        __builtin_amdgcn_s_setprio(1);
        #pragma unroll
        for (int mi = 0; mi < 4; mi++)
            #pragma unroll
            for (int ni = 0; ni < 4; ni++)
                acc[mi][ni] = __builtin_amdgcn_mfma_f32_16x16x32_bf16(a[mi], b[ni], acc[mi][ni], 0, 0, 0);
        __builtin_amdgcn_s_setprio(0);
        __builtin_amdgcn_s_barrier();
        __builtin_amdgcn_sched_barrier(0);
        cur ^= 1;
    }

    size_t MN = (size_t)N * (size_t)(gridDim.y * 256);
    float* Pz = P + (size_t)z * MN;
    #pragma unroll
    for (int mi = 0; mi < 4; mi++) {
        int r0 = bm + wr * 64 + mi * 16 + (lane >> 4) * 4;
        #pragma unroll
        for (int ni = 0; ni < 4; ni++) {
            int c = bn + wc * 64 + ni * 16 + (lane & 15);
            #pragma unroll
            for (int j = 0; j < 4; j++)
                Pz[(size_t)(r0 + j) * N + c] = acc[mi][ni][j];
        }
    }
}

// ---------------- split-K reduce + epilogue ----------------
template <int OUT_BF16>
__global__ __launch_bounds__(256) void k_reduce(const float* __restrict__ P, int S, int MN, int N,
                                                void* __restrict__ Cout, int ldc,
                                                const float* __restrict__ bias, float scale,
                                                int useLeaky) {
    int idx = (blockIdx.x * 256 + threadIdx.x) * 4;
    if (idx >= MN) return;
    float4 v = *(const float4*)(P + idx);
    for (int s = 1; s < S; s++) {
        float4 t = *(const float4*)(P + (size_t)s * MN + idx);
        v.x += t.x; v.y += t.y; v.z += t.z; v.w += t.w;
    }
    int m = idx / N, n = idx - m * N;
    float vv[4] = {v.x, v.y, v.z, v.w};
    #pragma unroll
    for (int j = 0; j < 4; j++) {
        float x = vv[j] * scale + bias[n + j];
        if (useLeaky) x = x >= 0.f ? x : 0.01f * x;
        if (OUT_BF16) ((unsigned short*)Cout)[(size_t)m * ldc + n + j] = f2bf(x);
        else ((float*)Cout)[(size_t)m * ldc + n + j] = x;
    }
}

// ---------------- final score ----------------
__global__ void k_score(const float* __restrict__ h2, const float* __restrict__ W3,
                        const float* __restrict__ b3, float* __restrict__ out) {
    int p = blockIdx.x;
    int lane = threadIdx.x;
    const float* r = h2 + (size_t)p * 128;
    float s = r[lane] * W3[lane] + r[lane + 64] * W3[lane + 64];
    for (int o = 32; o; o >>= 1) s += __shfl_down(s, o);
    if (lane == 0) out[p] = s + b3[0];
}

extern "C" void kernel_launch(void* const* d_in, const int* in_sizes, int n_in,
                              void* d_out, int out_size, void* d_ws, size_t ws_size,
                              hipStream_t stream) {
    const float* x_skill = (const float*)d_in[0];
    const float* x_job   = (const float*)d_in[1];
    const float* x_resume= (const float*)d_in[2];
    const float* W_rel   = (const float*)d_in[3];
    const float* b_rel   = (const float*)d_in[4];
    const float* W_root  = (const float*)d_in[5];
    const float* W_gs    = (const float*)d_in[6];
    const float* W_gd    = (const float*)d_in[7];
    const float* att_s   = (const float*)d_in[8];
    const float* att_d   = (const float*)d_in[9];
    const float* b_gat   = (const float*)d_in[10];
    const float* W1      = (const float*)d_in[11];
    const float* b1      = (const float*)d_in[12];
    const float* W2      = (const float*)d_in[13];
    const float* b2      = (const float*)d_in[14];
    const float* W3      = (const float*)d_in[15];
    const float* b3      = (const float*)d_in[16];
    const int* esj = (const int*)d_in[17];
    const int* edj = (const int*)d_in[18];
    const int* esr = (const int*)d_in[19];
    const int* edr = (const int*)d_in[20];

    const int NS = in_sizes[0] / D_;
    const int NP = in_sizes[1] / D_;
    const int EJ = in_sizes[17];
    const int ER = in_sizes[19];

    float* score = (float*)d_out;
    float* alpha = score + NP;

    char* ws = (char*)d_ws;
    size_t off = 0;
    auto alloc = [&](size_t bytes) -> void* {
        void* p = ws + off;
        off = (off + bytes + 255) & ~(size_t)255;
        return p;
    };

    int* cnt_j  = (int*)alloc((size_t)4 * NP * sizeof(int));
    int* fill_j = cnt_j + NP;
    int* cnt_r  = cnt_j + 2 * NP;
    int* fill_r = cnt_j + 3 * NP;
    int* off_j  = (int*)alloc((size_t)(NP + 1) * sizeof(int));
    int* off_r  = (int*)alloc((size_t)(NP + 1) * sizeof(int));
    int* sid_j  = (int*)alloc((size_t)EJ * sizeof(int));
    int* sid_r  = (int*)alloc((size_t)ER * sizeof(int));
    float* Vsrc = (float*)alloc((size_t)D_ * H_ * 4);
    float* Vdst = (float*)alloc((size_t)D_ * H_ * 4);
    float* a_src= (float*)alloc((size_t)NS * H_ * 4);
    float* a_dst= (float*)alloc((size_t)NP * H_ * 4);
    unsigned short* cat_in = (unsigned short*)alloc((size_t)NP * 2 * D_ * 2);
    unsigned short* aggatt = (unsigned short*)alloc((size_t)NP * H_ * D_ * 2);
    unsigned short* BT1    = (unsigned short*)alloc((size_t)D_ * 2 * D_ * 2);
    unsigned short* BTg    = (unsigned short*)alloc((size_t)D_ * H_ * D_ * 2);
    unsigned short* BTw1   = (unsigned short*)alloc((size_t)512 * 2 * D_ * 2);
    unsigned short* BTw2   = (unsigned short*)alloc((size_t)128 * 512 * 2);
    unsigned short* hcat   = (unsigned short*)alloc((size_t)NP * 2 * D_ * 2);
    unsigned short* h1b    = (unsigned short*)alloc((size_t)NP * 512 * 2);
    float* h2   = (float*)alloc((size_t)NP * 128 * 4);
    // Pbuf: max(5*NP*D, 16*NP*512, 16*NP*128) floats = 16*NP*512
    float* Pbuf = (float*)alloc((size_t)16 * NP * 512 * 4);
    unsigned* xsb = (unsigned*)Pbuf;   // alias: xsb dead before first GEMM writes Pbuf

    hipMemsetAsync(cnt_j, 0, (size_t)4 * NP * sizeof(int), stream);

    k_tr<0><<<dim3(D_ / 64, D_ / 64), 256, 0, stream>>>(W_rel, D_, BT1, 2 * D_);
    k_tr<0><<<dim3(D_ / 64, D_ / 64), 256, 0, stream>>>(W_root, D_, BT1 + D_, 2 * D_);
    k_tr<1><<<dim3(D_ / 64, (H_ * D_) / 64), 256, 0, stream>>>(W_gs, 0, BTg, H_ * D_);
    k_tr<0><<<dim3(512 / 64, (2 * D_) / 64), 256, 0, stream>>>(W1, 512, BTw1, 2 * D_);
    k_tr<0><<<dim3(128 / 64, 512 / 64), 256, 0, stream>>>(W2, 128, BTw2, 512);

    k_xsb<<<NS, 256, 0, stream>>>(x_skill, xsb);
    k_vmat<<<2 * D_ * H_, 256, 0, stream>>>(W_gs, W_gd, att_s, att_d, Vsrc, Vdst);
    k_a<<<NS, 256, 0, stream>>>(x_skill, Vsrc, a_src, NS);
    k_a<<<NP, 256, 0, stream>>>(x_resume, Vdst, a_dst, NP);

    int egrid = (EJ + ER + 255) / 256;
    k_count<<<egrid, 256, 0, stream>>>(edj, EJ, edr, ER, cnt_j, cnt_r);
    k_scan<<<2, 64, 0, stream>>>(cnt_j, off_j, cnt_r, off_r, NP);
    k_scatter<<<egrid, 256, 0, stream>>>(edj, EJ, edr, ER, off_j, fill_j, sid_j, off_r, fill_r, sid_r);

    k_agg<<<NP, 256, 0, stream>>>(xsb, esj, sid_j, cnt_j, off_j, (unsigned*)cat_in);
    k_xjob<<<NP, 256, 0, stream>>>(x_job, (unsigned*)cat_in);
    k_softmax<<<NP, 64, 0, stream>>>(a_src, a_dst, esr, sid_r, cnt_r, off_r, alpha);
    k_aggatt<<<NP, 256, 0, stream>>>(xsb, alpha, esr, sid_r, cnt_r, off_r, (unsigned*)aggatt);

    const int MN_f = NP * D_;
    const int MN_1 = NP * 512;
    const int MN_2 = NP * 128;

    // hcat[:, :D] = leaky([agg|x_job] @ [W_rel;W_root] + b_rel)   K=3072 (96 steps), S=5
    gemm_sk<<<dim3(D_ / 128, NP / 256, 5), 512, 0, stream>>>(
        cat_in, 2 * D_, BT1, 2 * D_, Pbuf, D_, 19, 1);
    k_reduce<1><<<MN_f / 1024, 256, 0, stream>>>(Pbuf, 5, MN_f, D_, hcat, 2 * D_, b_rel, 1.f, 1);

    // hcat[:, D:] = leaky((1/H) * aggatt @ Wstack + b_gat)        K=12288 (384 steps), S=5
    gemm_sk<<<dim3(D_ / 128, NP / 256, 5), 512, 0, stream>>>(
        aggatt, H_ * D_, BTg, H_ * D_, Pbuf, D_, 76, 4);
    k_reduce<1><<<MN_f / 1024, 256, 0, stream>>>(Pbuf, 5, MN_f, D_, hcat + D_, 2 * D_, b_gat, 1.f / H_, 1);

    // h1 = leaky(hcat @ W1 + b1) -> bf16                          K=3072 (96 steps), S=16
    gemm_sk<<<dim3(512 / 128, NP / 256, 16), 512, 0, stream>>>(
        hcat, 2 * D_, BTw1, 2 * D_, Pbuf, 512, 6, 0);
    k_reduce<1><<<MN_1 / 1024, 256, 0, stream>>>(Pbuf, 16, MN_1, 512, h1b, 512, b1, 1.f, 1);

    // h2 = leaky(h1 @ W2 + b2) -> fp32                            K=512 (16 steps), S=16
    gemm_sk<<<dim3(128 / 128, NP / 256, 16), 512, 0, stream>>>(
        h1b, 512, BTw2, 512, Pbuf, 128, 1, 0);
    k_reduce<0><<<MN_2 / 1024, 256, 0, stream>>>(Pbuf, 16, MN_2, 128, h2, 128, b2, 1.f, 1);

    k_score<<<NP, 64, 0, stream>>>(h2, W3, b3, score);
}

// Round 6
// 449.050 us; speedup vs baseline: 5.4726x; 1.0068x over previous
//
#include <hip/hip_runtime.h>

#define D_ 1536
#define H_ 8

typedef __attribute__((ext_vector_type(8))) short bf16x8;
typedef __attribute__((ext_vector_type(4))) float f32x4;

__device__ __forceinline__ unsigned short f2bf(float f) {
    unsigned u = __builtin_bit_cast(unsigned, f);
    unsigned r = (u + 0x7fffu + ((u >> 16) & 1u)) >> 16;
    return (unsigned short)r;
}

__device__ __forceinline__ unsigned pack2bf(float a, float b) {
    return (unsigned)f2bf(a) | ((unsigned)f2bf(b) << 16);
}

__device__ __forceinline__ float bflo(unsigned u) { return __builtin_bit_cast(float, u << 16); }
__device__ __forceinline__ float bfhi(unsigned u) { return __builtin_bit_cast(float, u & 0xffff0000u); }

__device__ __forceinline__ void gload16(const void* g, void* l) {
    __builtin_amdgcn_global_load_lds((const __attribute__((address_space(1))) void*)g,
                                     (__attribute__((address_space(3))) void*)l, 16, 0, 0);
}

// ---------------- V[d,h] = sum_d2 W[d, h*D+d2]*att[h,d2]  (float4, one block per d) ----------
__global__ __launch_bounds__(256) void k_vmat2(const float* __restrict__ Wsrc,
                                               const float* __restrict__ Wdst,
                                               const float* __restrict__ att_s,
                                               const float* __restrict__ att_d,
                                               float* __restrict__ Vsrc,
                                               float* __restrict__ Vdst) {
    int id = blockIdx.x;
    int sel = id >= D_;
    int d = sel ? id - D_ : id;
    const float4* wr = (const float4*)((sel ? Wdst : Wsrc) + (size_t)d * (H_ * D_));
    const float* at = sel ? att_d : att_s;
    int t = threadIdx.x;
    float part[H_];
    #pragma unroll
    for (int h = 0; h < H_; h++) {
        const float4* ar = (const float4*)(at + h * D_);
        float4 w0 = wr[h * 384 + t];
        float4 a0 = ar[t];
        float s = w0.x * a0.x + w0.y * a0.y + w0.z * a0.z + w0.w * a0.w;
        if (t < 128) {
            float4 w1 = wr[h * 384 + 256 + t];
            float4 a1 = ar[256 + t];
            s += w1.x * a1.x + w1.y * a1.y + w1.z * a1.z + w1.w * a1.w;
        }
        part[h] = s;
    }
    __shared__ float red[4][H_];
    int lane = t & 63, w = t >> 6;
    #pragma unroll
    for (int h = 0; h < H_; h++) {
        float v = part[h];
        for (int o = 32; o; o >>= 1) v += __shfl_down(v, o);
        if (lane == 0) red[w][h] = v;
    }
    __syncthreads();
    if (t < H_) (sel ? Vdst : Vsrc)[d * H_ + t] = red[0][t] + red[1][t] + red[2][t] + red[3][t];
}

// ---------------- a_src = x @ V  AND  xsb = bf16(x)  (fused single pass) ----------------
__global__ __launch_bounds__(256) void k_a_xsb(const float* __restrict__ x,
                                               const float* __restrict__ V,
                                               float* __restrict__ out,
                                               unsigned* __restrict__ xb) {
    int n = blockIdx.x;
    float part[H_] = {};
    const float2* xr = (const float2*)x + (size_t)n * 768;
    unsigned* ob = xb + (size_t)n * 768;
    #pragma unroll
    for (int j = 0; j < 3; j++) {
        int e = threadIdx.x + j * 256;
        float2 v = xr[e];
        ob[e] = pack2bf(v.x, v.y);
        const float* vp = V + (size_t)(2 * e) * H_;
        #pragma unroll
        for (int h = 0; h < H_; h++) part[h] += v.x * vp[h] + v.y * vp[h + H_];
    }
    __shared__ float red[4][H_];
    int lane = threadIdx.x & 63, w = threadIdx.x >> 6;
    #pragma unroll
    for (int h = 0; h < H_; h++) {
        float v = part[h];
        for (int o = 32; o; o >>= 1) v += __shfl_down(v, o);
        if (lane == 0) red[w][h] = v;
    }
    __syncthreads();
    if (threadIdx.x < H_)
        out[(size_t)n * H_ + threadIdx.x] =
            red[0][threadIdx.x] + red[1][threadIdx.x] + red[2][threadIdx.x] + red[3][threadIdx.x];
}

// ---------------- a_dst = x_resume @ Vdst ----------------
__global__ __launch_bounds__(256) void k_a(const float* __restrict__ x,
                                           const float* __restrict__ V,
                                           float* __restrict__ out, int N) {
    int n = blockIdx.x;
    if (n >= N) return;
    float part[H_] = {};
    const float* xr = x + (size_t)n * D_;
    #pragma unroll
    for (int j = 0; j < 6; j++) {
        int d = threadIdx.x + j * 256;
        float xv = xr[d];
        const float* vp = V + d * H_;
        #pragma unroll
        for (int h = 0; h < H_; h++) part[h] += xv * vp[h];
    }
    __shared__ float red[4][H_];
    int lane = threadIdx.x & 63, w = threadIdx.x >> 6;
    #pragma unroll
    for (int h = 0; h < H_; h++) {
        float v = part[h];
        for (int o = 32; o; o >>= 1) v += __shfl_down(v, o);
        if (lane == 0) red[w][h] = v;
    }
    __syncthreads();
    if (threadIdx.x < H_)
        out[(size_t)n * H_ + threadIdx.x] =
            red[0][threadIdx.x] + red[1][threadIdx.x] + red[2][threadIdx.x] + red[3][threadIdx.x];
}

// ---------------- edge counting sort ----------------
__global__ void k_count(const int* __restrict__ dj, int ej, const int* __restrict__ dr, int er,
                        int* cnt_j, int* cnt_r) {
    int i = blockIdx.x * blockDim.x + threadIdx.x;
    if (i < ej) atomicAdd(&cnt_j[dj[i]], 1);
    else if (i < ej + er) atomicAdd(&cnt_r[dr[i - ej]], 1);
}

__global__ void k_scan(const int* __restrict__ cnt_j, int* off_j,
                       const int* __restrict__ cnt_r, int* off_r, int NP) {
    const int* cnt = blockIdx.x ? cnt_r : cnt_j;
    int* off = blockIdx.x ? off_r : off_j;
    int lane = threadIdx.x;
    int chunk = (NP + 63) / 64;
    int base = lane * chunk;
    int sum = 0;
    for (int i = 0; i < chunk; i++) { int idx = base + i; if (idx < NP) sum += cnt[idx]; }
    int incl = sum;
    for (int o = 1; o < 64; o <<= 1) { int t = __shfl_up(incl, o); if (lane >= o) incl += t; }
    int run = incl - sum;
    for (int i = 0; i < chunk; i++) { int idx = base + i; if (idx < NP) { off[idx] = run; run += cnt[idx]; } }
    if (lane == 63) off[NP] = run;
}

__global__ void k_scatter(const int* __restrict__ dj, int ej, const int* __restrict__ dr, int er,
                          const int* __restrict__ off_j, int* fill_j, int* sid_j,
                          const int* __restrict__ off_r, int* fill_r, int* sid_r) {
    int i = blockIdx.x * blockDim.x + threadIdx.x;
    if (i < ej) {
        int p = dj[i];
        int slot = atomicAdd(&fill_j[p], 1);
        sid_j[off_j[p] + slot] = i;
    } else if (i < ej + er) {
        int e = i - ej;
        int p = dr[e];
        int slot = atomicAdd(&fill_r[p], 1);
        sid_r[off_r[p] + slot] = e;
    }
}

// ---------------- GraphConv aggregate (bf16 gather) + x_job convert -> cat_in ----------------
__global__ __launch_bounds__(256) void k_agg(const unsigned* __restrict__ xb, const int* __restrict__ src,
                                             const int* __restrict__ sid, const int* __restrict__ cnt,
                                             const int* __restrict__ off,
                                             const float* __restrict__ x_job,
                                             unsigned* __restrict__ cat_u) {
    int p = blockIdx.x;
    int n = cnt[p], o = off[p];
    float2 acc[3] = {};
    int i = 0;
    for (; i + 2 <= n; i += 2) {
        int e0 = sid[o + i], e1 = sid[o + i + 1];
        const unsigned* r0 = xb + (size_t)src[e0] * 768 + threadIdx.x;
        const unsigned* r1 = xb + (size_t)src[e1] * 768 + threadIdx.x;
        unsigned v0[3], v1[3];
        #pragma unroll
        for (int j = 0; j < 3; j++) { v0[j] = r0[j * 256]; v1[j] = r1[j * 256]; }
        #pragma unroll
        for (int j = 0; j < 3; j++) {
            acc[j].x += bflo(v0[j]) + bflo(v1[j]);
            acc[j].y += bfhi(v0[j]) + bfhi(v1[j]);
        }
    }
    if (i < n) {
        int e0 = sid[o + i];
        const unsigned* r0 = xb + (size_t)src[e0] * 768 + threadIdx.x;
        #pragma unroll
        for (int j = 0; j < 3; j++) { unsigned v = r0[j * 256]; acc[j].x += bflo(v); acc[j].y += bfhi(v); }
    }
    unsigned* orow = cat_u + (size_t)p * 1536 + threadIdx.x;
    #pragma unroll
    for (int j = 0; j < 3; j++) orow[j * 256] = pack2bf(acc[j].x, acc[j].y);
    // fused x_job -> bf16 into cat[:, D:2D]
    const float2* xjr = (const float2*)x_job + (size_t)p * 768 + threadIdx.x;
    #pragma unroll
    for (int j = 0; j < 3; j++) { float2 v = xjr[j * 256]; orow[768 + j * 256] = pack2bf(v.x, v.y); }
}

// ---------------- GAT segment softmax -> alpha (fp32, original edge order) ----------------
__global__ void k_softmax(const float* __restrict__ a_src, const float* __restrict__ a_dst,
                          const int* __restrict__ src, const int* __restrict__ sid,
                          const int* __restrict__ cnt, const int* __restrict__ off,
                          float* __restrict__ alpha_out) {
    int p = blockIdx.x;
    int n = cnt[p], o = off[p];
    if (n == 0) return;
    int lane = threadIdx.x;
    #pragma unroll 1
    for (int h = 0; h < H_; h++) {
        float ad = a_dst[(size_t)p * H_ + h];
        float m = -3.4e38f;
        for (int i = lane; i < n; i += 64) {
            int e = sid[o + i];
            float v = a_src[(size_t)src[e] * H_ + h] + ad;
            v = v >= 0.f ? v : 0.2f * v;
            m = fmaxf(m, v);
        }
        for (int o2 = 32; o2; o2 >>= 1) m = fmaxf(m, __shfl_xor(m, o2));
        float s = 0.f;
        for (int i = lane; i < n; i += 64) {
            int e = sid[o + i];
            float v = a_src[(size_t)src[e] * H_ + h] + ad;
            v = v >= 0.f ? v : 0.2f * v;
            s += expf(v - m);
        }
        for (int o2 = 32; o2; o2 >>= 1) s += __shfl_xor(s, o2);
        float inv = 1.f / (s + 1e-16f);
        for (int i = lane; i < n; i += 64) {
            int e = sid[o + i];
            float v = a_src[(size_t)src[e] * H_ + h] + ad;
            v = v >= 0.f ? v : 0.2f * v;
            alpha_out[(size_t)e * H_ + h] = expf(v - m) * inv;
        }
    }
}

// ---------------- attention-weighted aggregate (bf16 gather) -> aggatt bf16 ----------------
__global__ __launch_bounds__(256) void k_aggatt(const unsigned* __restrict__ xb,
                                                const float* __restrict__ alpha,
                                                const int* __restrict__ src, const int* __restrict__ sid,
                                                const int* __restrict__ cnt, const int* __restrict__ off,
                                                unsigned* __restrict__ aggatt_u) {
    int p = blockIdx.x;
    int n = cnt[p], o = off[p];
    float2 acc[H_][3] = {};
    int i = 0;
    for (; i + 2 <= n; i += 2) {
        int e0 = sid[o + i], e1 = sid[o + i + 1];
        const unsigned* r0 = xb + (size_t)src[e0] * 768 + threadIdx.x;
        const unsigned* r1 = xb + (size_t)src[e1] * 768 + threadIdx.x;
        unsigned v0[3], v1[3];
        #pragma unroll
        for (int j = 0; j < 3; j++) { v0[j] = r0[j * 256]; v1[j] = r1[j * 256]; }
        const float* a0 = alpha + (size_t)e0 * H_;
        const float* a1 = alpha + (size_t)e1 * H_;
        float f0[3][2], f1[3][2];
        #pragma unroll
        for (int j = 0; j < 3; j++) {
            f0[j][0] = bflo(v0[j]); f0[j][1] = bfhi(v0[j]);
            f1[j][0] = bflo(v1[j]); f1[j][1] = bfhi(v1[j]);
        }
        #pragma unroll
        for (int h = 0; h < H_; h++) {
            float w0 = a0[h], w1 = a1[h];
            #pragma unroll
            for (int j = 0; j < 3; j++) {
                acc[h][j].x += w0 * f0[j][0] + w1 * f1[j][0];
                acc[h][j].y += w0 * f0[j][1] + w1 * f1[j][1];
            }
        }
    }
    if (i < n) {
        int e0 = sid[o + i];
        const unsigned* r0 = xb + (size_t)src[e0] * 768 + threadIdx.x;
        unsigned v0[3];
        #pragma unroll
        for (int j = 0; j < 3; j++) v0[j] = r0[j * 256];
        const float* a0 = alpha + (size_t)e0 * H_;
        #pragma unroll
        for (int h = 0; h < H_; h++) {
            float w0 = a0[h];
            #pragma unroll
            for (int j = 0; j < 3; j++) {
                acc[h][j].x += w0 * bflo(v0[j]);
                acc[h][j].y += w0 * bfhi(v0[j]);
            }
        }
    }
    unsigned* orow = aggatt_u + (size_t)p * (H_ * 768) + threadIdx.x;
    #pragma unroll
    for (int h = 0; h < H_; h++)
        #pragma unroll
        for (int j = 0; j < 3; j++)
            orow[h * 768 + j * 256] = pack2bf(acc[h][j].x, acc[h][j].y);
}

// ---------------- fp32 [K][N] -> bf16 [N][K] transpose (u32-packed stores) ----------------
template <int GATB>
__global__ __launch_bounds__(256) void k_tr(const float* __restrict__ in, int ldin,
                                            unsigned short* __restrict__ out, int ldout) {
    __shared__ float t[64][65];
    int k0 = blockIdx.y * 64, n0 = blockIdx.x * 64;
    int tx = threadIdx.x & 63, ty = threadIdx.x >> 6;
    #pragma unroll
    for (int i = 0; i < 16; i++) {
        int k = k0 + ty + i * 4;
        const float* rp;
        if (GATB) {
            int d2 = k % D_, h = k / D_;
            rp = in + (size_t)d2 * (H_ * D_) + (size_t)h * D_;
        } else {
            rp = in + (size_t)k * ldin;
        }
        t[ty + i * 4][tx] = rp[n0 + tx];
    }
    __syncthreads();
    int tx2 = threadIdx.x & 31, ty2 = threadIdx.x >> 5;
    #pragma unroll
    for (int i = 0; i < 8; i++) {
        int nl = ty2 + i * 8;
        unsigned v = pack2bf(t[tx2 * 2][nl], t[tx2 * 2 + 1][nl]);
        *(unsigned*)(out + (size_t)(n0 + nl) * ldout + k0 + tx2 * 2) = v;
    }
}

// ---------------- bf16 MFMA GEMM: BM=256 BN=128, 8 waves, split-K, 3-buf 2-deep pipeline ------
__global__ __launch_bounds__(512, 4) void gemm_sk(const unsigned short* __restrict__ A, int lda,
                                                  const unsigned short* __restrict__ BT, int ldb,
                                                  float* __restrict__ P, int N, int bs, int extra) {
    __shared__ unsigned short As[3][256 * 32];
    __shared__ unsigned short Bs[3][128 * 32];
    int tid = threadIdx.x;
    int lane = tid & 63, wid = tid >> 6;

    int nwg = gridDim.x * gridDim.y;
    int bidh = blockIdx.y * gridDim.x + blockIdx.x;
    int swz = (bidh & 7) * (nwg >> 3) + (bidh >> 3);
    int bn = (swz % gridDim.x) * 128;
    int bm = (swz / gridDim.x) * 256;

    int z = blockIdx.z;
    int nt = bs + (z < extra);
    int kb = z * bs + min(z, extra);
    int kbase = kb * 32;

    int wr = wid >> 1, wc = wid & 1;            // 4 x 2 wave grid, wave tile 64x64
    int fr = lane & 15, g = lane >> 4;

    int ra0 = tid >> 2, sa0 = tid & 3;
    int ra1 = (tid + 512) >> 2;
    int sg_a0 = sa0 ^ ((ra0 >> 1) & 3);
    int sg_a1 = sa0 ^ ((ra1 >> 1) & 3);
    int sg_b = sg_a0;

    f32x4 acc[4][4] = {};

    auto stage = [&](int buf, int k0) {
        gload16(A + (size_t)(bm + ra0) * lda + k0 + sg_a0 * 8, &As[buf][tid * 8]);
        gload16(A + (size_t)(bm + ra1) * lda + k0 + sg_a1 * 8, &As[buf][(tid + 512) * 8]);
        gload16(BT + (size_t)(bn + ra0) * ldb + k0 + sg_b * 8, &Bs[buf][tid * 8]);
    };

    stage(0, kbase);
    if (nt > 1) stage(1, kbase + 32);
    for (int t = 0; t < nt; t++) {
        if (t + 2 < nt) {
            stage((t + 2) % 3, kbase + (t + 2) * 32);
            asm volatile("s_waitcnt vmcnt(6)" ::: "memory");   // oldest stage (t) landed
        } else if (t + 1 < nt) {
            asm volatile("s_waitcnt vmcnt(3)" ::: "memory");
        } else {
            asm volatile("s_waitcnt vmcnt(0)" ::: "memory");
        }
        __builtin_amdgcn_s_barrier();
        __builtin_amdgcn_sched_barrier(0);
        int cur = t % 3;
        bf16x8 a[4], b[4];
        #pragma unroll
        for (int mi = 0; mi < 4; mi++) {
            int row = wr * 64 + mi * 16 + fr;
            a[mi] = *(const bf16x8*)(&As[cur][row * 32 + ((g ^ ((row >> 1) & 3)) * 8)]);
        }
        #pragma unroll
        for (int ni = 0; ni < 4; ni++) {
            int row = wc * 64 + ni * 16 + fr;
            b[ni] = *(const bf16x8*)(&Bs[cur][row * 32 + ((g ^ ((row >> 1) & 3)) * 8)]);
        }
        __builtin_amdgcn_s_setprio(1);
        #pragma unroll
        for (int mi = 0; mi < 4; mi++)
            #pragma unroll
            for (int ni = 0; ni < 4; ni++)
                acc[mi][ni] = __builtin_amdgcn_mfma_f32_16x16x32_bf16(a[mi], b[ni], acc[mi][ni], 0, 0, 0);
        __builtin_amdgcn_s_setprio(0);
        __builtin_amdgcn_s_barrier();
        __builtin_amdgcn_sched_barrier(0);
    }

    size_t MN = (size_t)N * (size_t)(gridDim.y * 256);
    float* Pz = P + (size_t)z * MN;
    #pragma unroll
    for (int mi = 0; mi < 4; mi++) {
        int r0 = bm + wr * 64 + mi * 16 + (lane >> 4) * 4;
        #pragma unroll
        for (int ni = 0; ni < 4; ni++) {
            int c = bn + wc * 64 + ni * 16 + (lane & 15);
            #pragma unroll
            for (int j = 0; j < 4; j++)
                Pz[(size_t)(r0 + j) * N + c] = acc[mi][ni][j];
        }
    }
}

// ---------------- split-K reduce + epilogue ----------------
template <int OUT_BF16>
__global__ __launch_bounds__(256) void k_reduce(const float* __restrict__ P, int S, int MN, int N,
                                                void* __restrict__ Cout, int ldc,
                                                const float* __restrict__ bias, float scale,
                                                int useLeaky) {
    int idx = (blockIdx.x * 256 + threadIdx.x) * 4;
    if (idx >= MN) return;
    float4 v = *(const float4*)(P + idx);
    for (int s = 1; s < S; s++) {
        float4 t = *(const float4*)(P + (size_t)s * MN + idx);
        v.x += t.x; v.y += t.y; v.z += t.z; v.w += t.w;
    }
    int m = idx / N, n = idx - m * N;
    float vv[4] = {v.x, v.y, v.z, v.w};
    #pragma unroll
    for (int j = 0; j < 4; j++) {
        float x = vv[j] * scale + bias[n + j];
        if (useLeaky) x = x >= 0.f ? x : 0.01f * x;
        if (OUT_BF16) ((unsigned short*)Cout)[(size_t)m * ldc + n + j] = f2bf(x);
        else ((float*)Cout)[(size_t)m * ldc + n + j] = x;
    }
}

// ---------------- fused MLP2 + score: h1b[2048,512]bf16 -> h2=leaky(h1@W2+b2) -> score ------
__global__ __launch_bounds__(256) void k_mlp2(const unsigned short* __restrict__ h1b,
                                              const float* __restrict__ W2,
                                              const float* __restrict__ b2,
                                              const float* __restrict__ W3,
                                              const float* __restrict__ b3,
                                              float* __restrict__ score) {
    __shared__ unsigned h1s[8][256];     // 8 rows x 512 bf16
    __shared__ float red[4][4];
    int p0 = blockIdx.x * 8;
    int tid = threadIdx.x;
    const unsigned* hsrc = (const unsigned*)h1b + (size_t)p0 * 256;
    #pragma unroll
    for (int i = 0; i < 8; i++) {
        int idx = tid + i * 256;
        h1s[idx >> 8][idx & 255] = hsrc[idx];
    }
    __syncthreads();
    int c = tid & 127, rg = tid >> 7;    // col 0..127, row-group 0..1 (rows rg*4..rg*4+3)
    float acc[4] = {};
    for (int k = 0; k < 512; k += 2) {
        float w0 = W2[(size_t)k * 128 + c];
        float w1 = W2[(size_t)(k + 1) * 128 + c];
        #pragma unroll
        for (int r = 0; r < 4; r++) {
            unsigned hv = h1s[rg * 4 + r][k >> 1];
            acc[r] += bflo(hv) * w0 + bfhi(hv) * w1;
        }
    }
    float w3 = W3[c];
    float pr[4];
    #pragma unroll
    for (int r = 0; r < 4; r++) {
        float v = acc[r] + b2[c];
        v = v >= 0.f ? v : 0.01f * v;
        pr[r] = v * w3;
    }
    #pragma unroll
    for (int r = 0; r < 4; r++)
        for (int o = 32; o; o >>= 1) pr[r] += __shfl_down(pr[r], o);
    int w = tid >> 6;                    // wave 0..3; waves 0,1 -> rg0, waves 2,3 -> rg1
    if ((tid & 63) == 0) {
        #pragma unroll
        for (int r = 0; r < 4; r++) red[w][r] = pr[r];
    }
    __syncthreads();
    if (tid < 8) {
        int rg2 = tid >> 2, r = tid & 3;
        float s = red[rg2 * 2][r] + red[rg2 * 2 + 1][r] + b3[0];
        score[p0 + rg2 * 4 + r] = s;
    }
}

extern "C" void kernel_launch(void* const* d_in, const int* in_sizes, int n_in,
                              void* d_out, int out_size, void* d_ws, size_t ws_size,
                              hipStream_t stream) {
    const float* x_skill = (const float*)d_in[0];
    const float* x_job   = (const float*)d_in[1];
    const float* x_resume= (const float*)d_in[2];
    const float* W_rel   = (const float*)d_in[3];
    const float* b_rel   = (const float*)d_in[4];
    const float* W_root  = (const float*)d_in[5];
    const float* W_gs    = (const float*)d_in[6];
    const float* W_gd    = (const float*)d_in[7];
    const float* att_s   = (const float*)d_in[8];
    const float* att_d   = (const float*)d_in[9];
    const float* b_gat   = (const float*)d_in[10];
    const float* W1      = (const float*)d_in[11];
    const float* b1      = (const float*)d_in[12];
    const float* W2      = (const float*)d_in[13];
    const float* b2      = (const float*)d_in[14];
    const float* W3      = (const float*)d_in[15];
    const float* b3      = (const float*)d_in[16];
    const int* esj = (const int*)d_in[17];
    const int* edj = (const int*)d_in[18];
    const int* esr = (const int*)d_in[19];
    const int* edr = (const int*)d_in[20];

    const int NS = in_sizes[0] / D_;
    const int NP = in_sizes[1] / D_;
    const int EJ = in_sizes[17];
    const int ER = in_sizes[19];

    float* score = (float*)d_out;
    float* alpha = score + NP;

    char* ws = (char*)d_ws;
    size_t off = 0;
    auto alloc = [&](size_t bytes) -> void* {
        void* p = ws + off;
        off = (off + bytes + 255) & ~(size_t)255;
        return p;
    };

    int* cnt_j  = (int*)alloc((size_t)4 * NP * sizeof(int));
    int* fill_j = cnt_j + NP;
    int* cnt_r  = cnt_j + 2 * NP;
    int* fill_r = cnt_j + 3 * NP;
    int* off_j  = (int*)alloc((size_t)(NP + 1) * sizeof(int));
    int* off_r  = (int*)alloc((size_t)(NP + 1) * sizeof(int));
    int* sid_j  = (int*)alloc((size_t)EJ * sizeof(int));
    int* sid_r  = (int*)alloc((size_t)ER * sizeof(int));
    float* Vsrc = (float*)alloc((size_t)D_ * H_ * 4);
    float* Vdst = (float*)alloc((size_t)D_ * H_ * 4);
    float* a_src= (float*)alloc((size_t)NS * H_ * 4);
    float* a_dst= (float*)alloc((size_t)NP * H_ * 4);
    unsigned short* cat_in = (unsigned short*)alloc((size_t)NP * 2 * D_ * 2);
    unsigned short* aggatt = (unsigned short*)alloc((size_t)NP * H_ * D_ * 2);
    unsigned short* BT1    = (unsigned short*)alloc((size_t)D_ * 2 * D_ * 2);
    unsigned short* BTg    = (unsigned short*)alloc((size_t)D_ * H_ * D_ * 2);
    unsigned short* BTw1   = (unsigned short*)alloc((size_t)512 * 2 * D_ * 2);
    unsigned short* hcat   = (unsigned short*)alloc((size_t)NP * 2 * D_ * 2);
    unsigned short* h1b    = (unsigned short*)alloc((size_t)NP * 512 * 2);
    // Pbuf: max(5*NP*D, 8*NP*512) floats = 5*NP*D
    float* Pbuf = (float*)alloc((size_t)5 * NP * D_ * 4);
    unsigned* xsb = (unsigned*)Pbuf;   // alias: xsb dead before first GEMM writes Pbuf

    hipMemsetAsync(cnt_j, 0, (size_t)4 * NP * sizeof(int), stream);

    k_tr<0><<<dim3(D_ / 64, D_ / 64), 256, 0, stream>>>(W_rel, D_, BT1, 2 * D_);
    k_tr<0><<<dim3(D_ / 64, D_ / 64), 256, 0, stream>>>(W_root, D_, BT1 + D_, 2 * D_);
    k_tr<1><<<dim3(D_ / 64, (H_ * D_) / 64), 256, 0, stream>>>(W_gs, 0, BTg, H_ * D_);
    k_tr<0><<<dim3(512 / 64, (2 * D_) / 64), 256, 0, stream>>>(W1, 512, BTw1, 2 * D_);

    k_vmat2<<<2 * D_, 256, 0, stream>>>(W_gs, W_gd, att_s, att_d, Vsrc, Vdst);
    k_a_xsb<<<NS, 256, 0, stream>>>(x_skill, Vsrc, a_src, xsb);
    k_a<<<NP, 256, 0, stream>>>(x_resume, Vdst, a_dst, NP);

    int egrid = (EJ + ER + 255) / 256;
    k_count<<<egrid, 256, 0, stream>>>(edj, EJ, edr, ER, cnt_j, cnt_r);
    k_scan<<<2, 64, 0, stream>>>(cnt_j, off_j, cnt_r, off_r, NP);
    k_scatter<<<egrid, 256, 0, stream>>>(edj, EJ, edr, ER, off_j, fill_j, sid_j, off_r, fill_r, sid_r);

    k_agg<<<NP, 256, 0, stream>>>(xsb, esj, sid_j, cnt_j, off_j, x_job, (unsigned*)cat_in);
    k_softmax<<<NP, 64, 0, stream>>>(a_src, a_dst, esr, sid_r, cnt_r, off_r, alpha);
    k_aggatt<<<NP, 256, 0, stream>>>(xsb, alpha, esr, sid_r, cnt_r, off_r, (unsigned*)aggatt);

    const int MN_f = NP * D_;
    const int MN_1 = NP * 512;

    // hcat[:, :D] = leaky([agg|x_job] @ [W_rel;W_root] + b_rel)   K=3072 (96 steps), S=5
    gemm_sk<<<dim3(D_ / 128, NP / 256, 5), 512, 0, stream>>>(
        cat_in, 2 * D_, BT1, 2 * D_, Pbuf, D_, 19, 1);
    k_reduce<1><<<MN_f / 1024, 256, 0, stream>>>(Pbuf, 5, MN_f, D_, hcat, 2 * D_, b_rel, 1.f, 1);

    // hcat[:, D:] = leaky((1/H) * aggatt @ Wstack + b_gat)        K=12288 (384 steps), S=5
    gemm_sk<<<dim3(D_ / 128, NP / 256, 5), 512, 0, stream>>>(
        aggatt, H_ * D_, BTg, H_ * D_, Pbuf, D_, 76, 4);
    k_reduce<1><<<MN_f / 1024, 256, 0, stream>>>(Pbuf, 5, MN_f, D_, hcat + D_, 2 * D_, b_gat, 1.f / H_, 1);

    // h1 = leaky(hcat @ W1 + b1) -> bf16                          K=3072 (96 steps), S=8
    gemm_sk<<<dim3(512 / 128, NP / 256, 8), 512, 0, stream>>>(
        hcat, 2 * D_, BTw1, 2 * D_, Pbuf, 512, 12, 0);
    k_reduce<1><<<MN_1 / 1024, 256, 0, stream>>>(Pbuf, 8, MN_1, 512, h1b, 512, b1, 1.f, 1);

    // h2 + score fused
    k_mlp2<<<NP / 8, 256, 0, stream>>>(h1b, W2, b2, W3, b3, score);
}